// Round 3
// baseline (40592.740 us; speedup 1.0000x reference)
//
#include <hip/hip_runtime.h>
#include <cstdint>
#include <cmath>

// ---------------- dims ----------------
#define NB    64      // batch
#define EMBD  300
#define EMBP  320     // padded K for embedding-side GEMMs
#define EH    512     // encoder hidden
#define DH    1024    // decoder hidden
#define GV    23262   // target vocab
#define GVP   23296   // padded to 182*128
#define TSRC  50
#define TDEC  49      // decoder steps
#define GRID  160     // persistent kernel workgroups (<=256 CUs -> co-resident)

typedef __attribute__((ext_vector_type(8))) short bf16x8;
typedef __attribute__((ext_vector_type(4))) float f32x4;

__device__ __forceinline__ unsigned short f2b(float f){
  union { float f; uint32_t u; } v; v.f = f;
  uint32_t u = (v.u + 0x7fffu + ((v.u >> 16) & 1u)) >> 16;
  return (unsigned short)u;
}
__device__ __forceinline__ float b2f(unsigned short h){
  union { uint32_t u; float f; } v; v.u = ((uint32_t)h) << 16;
  return v.f;
}
__device__ __forceinline__ float sigm(float x){ return 1.f/(1.f+expf(-x)); }

// acc[4] covers 64 batch rows x 16 W-rows (cols), K accumulation.
// a-frag lane l: A[(l&15)+16*m][k+(l>>4)*8+e]; b-frag lane l: W[wr+(l&15)][k+(l>>4)*8+e]
// d lane l reg e: D[m*16+(l>>4)*4+e][l&15]   (validated in round 2)
template<int K>
__device__ __forceinline__ void mm16(f32x4 (&acc)[4],
    const unsigned short* __restrict__ A, int lda,
    const unsigned short* __restrict__ Wr, int ldw, int lane)
{
  const int r = lane & 15, q = lane >> 4;
  const unsigned short* a0 = A + r*lda + q*8;
  const unsigned short* b0 = Wr + r*ldw + q*8;
#pragma unroll
  for (int k = 0; k < K; k += 32) {
    bf16x8 b = *(const bf16x8*)(b0 + k);
#pragma unroll
    for (int m = 0; m < 4; ++m) {
      bf16x8 a = *(const bf16x8*)(a0 + m*16*lda + k);
      acc[m] = __builtin_amdgcn_mfma_f32_16x16x32_bf16(a, b, acc[m], 0, 0, 0);
    }
  }
}

// ---------------- prep kernels ----------------
__global__ void cvt_pad(const float* __restrict__ src, unsigned short* __restrict__ dst,
                        int rows, int scols, int dcols)
{
  int idx = blockIdx.x*256 + threadIdx.x;
  if (idx >= rows*dcols) return;
  int c = idx % dcols, rr = idx / dcols;
  dst[idx] = (c < scols) ? f2b(src[(size_t)rr*scols + c]) : (unsigned short)0;
}

__global__ void cvt_split(const float* __restrict__ src,
                          unsigned short* __restrict__ hi, unsigned short* __restrict__ lo,
                          int rows, int scols, int dcols)
{
  int idx = blockIdx.x*256 + threadIdx.x;
  if (idx >= rows*dcols) return;
  int c = idx % dcols, rr = idx / dcols;
  float v = (c < scols) ? src[(size_t)rr*scols + c] : 0.f;
  unsigned short h = f2b(v);
  hi[idx] = h;
  lo[idx] = f2b(v - b2f(h));
}

__global__ void addb(const float* __restrict__ a, const float* __restrict__ b,
                     float* __restrict__ o, int n)
{
  int i = blockIdx.x*256 + threadIdx.x;
  if (i < n) o[i] = a[i] + b[i];
}

__global__ void k_embed(const int* __restrict__ src, const int* __restrict__ trg,
                        const float* __restrict__ eemb, const float* __restrict__ demb,
                        unsigned short* __restrict__ x_bf, unsigned short* __restrict__ xrev_bf,
                        unsigned short* __restrict__ pe_bf)
{
  int idx = blockIdx.x*256 + threadIdx.x;
  const int tot1 = TSRC*NB*EMBP;
  const int tot2 = TDEC*NB*EMBP;
  if (idx < tot1) {
    int e = idx % EMBP, rb = idx / EMBP;
    int t = rb >> 6, b = rb & 63;
    float v = 0.f;
    if (e < EMBD) v = eemb[(size_t)src[rb]*EMBD + e];
    unsigned short bv = f2b(v);
    x_bf[idx] = bv;
    xrev_bf[(size_t)((TSRC-1-t)*NB + b)*EMBP + e] = bv;
  } else if (idx < tot1 + tot2) {
    int k = idx - tot1;
    int e = k % EMBP, rb = k / EMBP;
    float v = 0.f;
    if (e < EMBD) v = demb[(size_t)trg[rb]*EMBD + e];
    pe_bf[k] = f2b(v);
  }
}

// ---------------- big tiled GEMM (throughput path: proj + generator) ----------------
__global__ __launch_bounds__(256) void gemm128(
    const unsigned short* __restrict__ A, int lda,
    const unsigned short* __restrict__ W, int ldw,
    const float* __restrict__ bias,
    float* __restrict__ out, int ldo,
    int K, int mvalid, int nvalid, int rowoff)
{
  __shared__ unsigned short As[128*64];
  __shared__ unsigned short Bs[128*64];
  const int tid = threadIdx.x;
  const int m0 = blockIdx.y*128, n0 = blockIdx.x*128;
  const int w = tid >> 6, lane = tid & 63, r = lane & 15, q = lane >> 4;
  const int mw = (w >> 1)*64, nw = (w & 1)*64;
  f32x4 acc[4][4];
#pragma unroll
  for (int mi=0; mi<4; ++mi)
#pragma unroll
    for (int ni=0; ni<4; ++ni) acc[mi][ni] = 0.f;

  for (int kt = 0; kt < K; kt += 64) {
    bf16x8 ra[4], rb[4];
#pragma unroll
    for (int j = 0; j < 4; ++j) {
      int c = j*256 + tid, row = c >> 3, cc = c & 7;
      ra[j] = *(const bf16x8*)(A + (size_t)(m0+row)*lda + kt + cc*8);
      rb[j] = *(const bf16x8*)(W + (size_t)(n0+row)*ldw + kt + cc*8);
    }
    __syncthreads();
#pragma unroll
    for (int j = 0; j < 4; ++j) {
      int c = j*256 + tid, row = c >> 3, cc = c & 7;
      int sw = cc ^ (row & 7);
      *(bf16x8*)((char*)As + row*128 + (sw<<4)) = ra[j];
      *(bf16x8*)((char*)Bs + row*128 + (sw<<4)) = rb[j];
    }
    __syncthreads();
#pragma unroll
    for (int kk = 0; kk < 64; kk += 32) {
      int ch = (kk >> 3) + q;
      bf16x8 av[4], bv[4];
#pragma unroll
      for (int mi=0; mi<4; ++mi) {
        int row = mw + mi*16 + r;
        av[mi] = *(const bf16x8*)((char*)As + row*128 + ((ch ^ (row&7))<<4));
      }
#pragma unroll
      for (int ni=0; ni<4; ++ni) {
        int row = nw + ni*16 + r;
        bv[ni] = *(const bf16x8*)((char*)Bs + row*128 + ((ch ^ (row&7))<<4));
      }
#pragma unroll
      for (int mi=0; mi<4; ++mi)
#pragma unroll
        for (int ni=0; ni<4; ++ni)
          acc[mi][ni] = __builtin_amdgcn_mfma_f32_16x16x32_bf16(av[mi], bv[ni], acc[mi][ni], 0,0,0);
    }
  }
#pragma unroll
  for (int mi=0; mi<4; ++mi)
#pragma unroll
    for (int ni=0; ni<4; ++ni)
#pragma unroll
      for (int e=0; e<4; ++e) {
        int mrow = m0 + mw + mi*16 + q*4 + e;
        int col  = n0 + nw + ni*16 + r;
        if (mrow < mvalid && col < nvalid)
          out[(size_t)(mrow + rowoff)*ldo + col] = acc[mi][ni][e] + bias[col];
      }
}

// ---------------- persistent sequential kernel (encoder + decoder) ----------------
struct SA {
  const unsigned short *whhFh, *whhFl, *whhRh, *whhRl;    // [2048][512]
  const unsigned short *wm1h, *wm1l;                      // [5120][1024]
  const unsigned short *woh, *wol;                        // [1024][2048]
  const unsigned short *w3h, *w3l;                        // [4096][1344]
  const unsigned short *pe;                               // [49][64][320]
  const float *xpF, *xpR;                                 // [50*64][2048] (bias included)
  const float *db4;                                       // [4096]
  unsigned short *hH, *hL;                                // [2 dir][2 buf][64][512]
  float *cF, *cR;                                         // [64][512]
  float *enc_out;                                         // [50][64][1024] fp32
  unsigned short *dhH, *dhL;                              // [64][1024]
  float *dc;                                              // [64][1024]
  float *q;                                               // [64][1024]
  float *gh;                                              // [64][4096]
  unsigned short *stH, *stL, *ctH, *ctL;                  // [64][1024]
  unsigned short *hdec;                                   // [3200][1024]
  int *bar;                                               // [cnt, gen]
};

__device__ __forceinline__ void gbar(int* bar, int nwg)
{
  __syncthreads();
  __threadfence();
  if (threadIdx.x == 0) {
    int* cnt = bar;
    int* gen = bar + 1;
    int g = __hip_atomic_load(gen, __ATOMIC_RELAXED, __HIP_MEMORY_SCOPE_AGENT);
    int v = __hip_atomic_fetch_add(cnt, 1, __ATOMIC_ACQ_REL, __HIP_MEMORY_SCOPE_AGENT);
    if (v == nwg - 1) {
      __hip_atomic_store(cnt, 0, __ATOMIC_RELAXED, __HIP_MEMORY_SCOPE_AGENT);
      __hip_atomic_fetch_add(gen, 1, __ATOMIC_ACQ_REL, __HIP_MEMORY_SCOPE_AGENT);
    } else {
      while (__hip_atomic_load(gen, __ATOMIC_ACQUIRE, __HIP_MEMORY_SCOPE_AGENT) == g) {}
    }
  }
  __syncthreads();
  __threadfence();
}

__global__ __launch_bounds__(256, 1) void seq_kernel(SA a)
{
  const int tid = threadIdx.x, w = tid >> 6, lane = tid & 63;
  const int nwg = gridDim.x, wgid = blockIdx.x;
  const int r = lane & 15, q4 = lane >> 4;
  __shared__ float sm4[4][64][16];
  __shared__ float qs[1024];
  __shared__ float sc[56];

  // ================= encoder: 50 steps =================
  for (int t = 0; t < TSRC; ++t) {
    const int cur = t & 1;
    for (int it = wgid; it < 64; it += nwg) {
      const int dir = it >> 5, j0 = (it & 31) << 4;
      const unsigned short* Whi = (dir ? a.whhRh : a.whhFh) + (size_t)(w*EH + j0)*EH;
      const unsigned short* Wlo = (dir ? a.whhRl : a.whhFl) + (size_t)(w*EH + j0)*EH;
      const unsigned short* Hh = a.hH + (size_t)(dir*2 + cur)*NB*EH;
      const unsigned short* Hl = a.hL + (size_t)(dir*2 + cur)*NB*EH;
      f32x4 acc[4];
#pragma unroll
      for (int m=0;m<4;++m) acc[m] = 0.f;
      mm16<EH>(acc, Hh, EH, Whi, EH, lane);
      mm16<EH>(acc, Hh, EH, Wlo, EH, lane);
      mm16<EH>(acc, Hl, EH, Whi, EH, lane);
#pragma unroll
      for (int m=0;m<4;++m)
#pragma unroll
        for (int e=0;e<4;++e) sm4[w][m*16 + q4*4 + e][r] = acc[m][e];
      __syncthreads();
      const float* xp = (dir ? a.xpR : a.xpF) + (size_t)t*NB*2048;
      float* C = dir ? a.cR : a.cF;
      unsigned short* HoH = a.hH + (size_t)(dir*2 + (cur^1))*NB*EH;
      unsigned short* HoL = a.hL + (size_t)(dir*2 + (cur^1))*NB*EH;
      const int erow = dir ? (TSRC-1 - t) : t;
      for (int p = tid; p < 1024; p += 256) {
        int b = p >> 4, jj = p & 15, j = j0 + jj;
        float gi = sm4[0][b][jj] + xp[b*2048 + 0*EH + j];
        float gf = sm4[1][b][jj] + xp[b*2048 + 1*EH + j];
        float gg = sm4[2][b][jj] + xp[b*2048 + 2*EH + j];
        float go = sm4[3][b][jj] + xp[b*2048 + 3*EH + j];
        float co = C[b*EH + j];
        float cn = sigm(gf)*co + sigm(gi)*tanhf(gg);
        float hn = sigm(go)*tanhf(cn);
        C[b*EH + j] = cn;
        unsigned short hb = f2b(hn);
        unsigned short lb = f2b(hn - b2f(hb));
        HoH[b*EH + j] = hb;
        HoL[b*EH + j] = lb;
        a.enc_out[((size_t)erow*NB + b)*DH + dir*EH + j] = hn;
        if (t == TSRC-1) {
          a.dhH[b*DH + 2*j + dir] = hb;
          a.dhL[b*DH + 2*j + dir] = lb;
          a.dc [b*DH + 2*j + dir] = cn;
        }
      }
      __syncthreads();
    }
    gbar(a.bar, nwg);
  }

  // ================= decoder: 49 steps =================
  for (int t = 0; t < TDEC; ++t) {
    // ---- P1: qgh = h @ [wi ; dWhh]^T (split, K split across wave pairs) ----
    for (int it = wgid; it < 160; it += nwg) {
      const int kh = w & 1, col0 = it*32 + (w >> 1)*16;
      const unsigned short* Whi = a.wm1h + (size_t)col0*DH + kh*512;
      const unsigned short* Wlo = a.wm1l + (size_t)col0*DH + kh*512;
      const unsigned short* Ah = a.dhH + kh*512;
      const unsigned short* Al = a.dhL + kh*512;
      f32x4 acc[4];
#pragma unroll
      for (int m=0;m<4;++m) acc[m] = 0.f;
      mm16<512>(acc, Ah, DH, Whi, DH, lane);
      mm16<512>(acc, Ah, DH, Wlo, DH, lane);
      mm16<512>(acc, Al, DH, Whi, DH, lane);
#pragma unroll
      for (int m=0;m<4;++m)
#pragma unroll
        for (int e=0;e<4;++e) sm4[w][m*16 + q4*4 + e][r] = acc[m][e];
      __syncthreads();
      for (int p = tid; p < 2048; p += 256) {
        int b = p >> 5, cc = p & 31;
        float v = sm4[(cc>>4)*2][b][cc&15] + sm4[(cc>>4)*2 + 1][b][cc&15];
        int C = it*32 + cc;
        if (C < 1024) a.q[b*DH + C] = v;
        else          a.gh[(size_t)b*4096 + C - 1024] = v;
      }
      __syncthreads();
    }
    gbar(a.bar, nwg);

    // ---- P2: attention per batch element ----
    for (int it = wgid; it < NB; it += nwg) {
      const int b = it;
      for (int i = tid; i < 1024; i += 256) qs[i] = a.q[b*DH + i];
      __syncthreads();
      for (int tt = w; tt < TSRC; tt += 4) {
        const float* er = a.enc_out + ((size_t)tt*NB + b)*DH + lane*16;
        const float* qq = qs + lane*16;
        float s = 0.f;
#pragma unroll
        for (int ii=0; ii<16; ++ii) s += er[ii]*qq[ii];
#pragma unroll
        for (int o=32; o; o>>=1) s += __shfl_xor(s, o);
        if (lane == 0) sc[tt] = s;
      }
      __syncthreads();
      float mx = -1e30f;
      for (int tt=0; tt<TSRC; ++tt) mx = fmaxf(mx, sc[tt]);
      __syncthreads();
      if (tid < TSRC) sc[tid] = expf(sc[tid] - mx);
      __syncthreads();
      float s50 = 0.f;
      for (int tt=0; tt<TSRC; ++tt) s50 += sc[tt];
      const float inv = 1.f/s50;
      const int c0 = tid*4;
      float a0=0.f, a1=0.f, a2=0.f, a3=0.f;
      for (int tt=0; tt<TSRC; ++tt) {
        float wt = sc[tt];
        const float* er = a.enc_out + ((size_t)tt*NB + b)*DH + c0;
        a0 += wt*er[0]; a1 += wt*er[1]; a2 += wt*er[2]; a3 += wt*er[3];
      }
      float av[4] = {a0*inv, a1*inv, a2*inv, a3*inv};
#pragma unroll
      for (int i=0;i<4;++i) {
        unsigned short hb = f2b(av[i]);
        a.stH[b*DH + c0 + i] = hb;
        a.stL[b*DH + c0 + i] = f2b(av[i] - b2f(hb));
      }
      __syncthreads();
    }
    gbar(a.bar, nwg);

    // ---- P3: ct = tanh([st,h] @ wo^T) (split; st/h halves across wave pairs) ----
    for (int it = wgid; it < 32; it += nwg) {
      const int kh = w & 1, col0 = it*32 + (w >> 1)*16;
      const unsigned short* Whi = a.woh + (size_t)col0*2048 + kh*1024;
      const unsigned short* Wlo = a.wol + (size_t)col0*2048 + kh*1024;
      const unsigned short* Ah = kh ? a.dhH : a.stH;
      const unsigned short* Al = kh ? a.dhL : a.stL;
      f32x4 acc[4];
#pragma unroll
      for (int m=0;m<4;++m) acc[m] = 0.f;
      mm16<1024>(acc, Ah, DH, Whi, 2048, lane);
      mm16<1024>(acc, Ah, DH, Wlo, 2048, lane);
      mm16<1024>(acc, Al, DH, Whi, 2048, lane);
#pragma unroll
      for (int m=0;m<4;++m)
#pragma unroll
        for (int e=0;e<4;++e) sm4[w][m*16 + q4*4 + e][r] = acc[m][e];
      __syncthreads();
      for (int p = tid; p < 2048; p += 256) {
        int b = p >> 5, cc = p & 31;
        float v = sm4[(cc>>4)*2][b][cc&15] + sm4[(cc>>4)*2 + 1][b][cc&15];
        float ct = tanhf(v);
        unsigned short hb = f2b(ct);
        int C = it*32 + cc;
        a.ctH[b*DH + C] = hb;
        a.ctL[b*DH + C] = f2b(ct - b2f(hb));
      }
      __syncthreads();
    }
    gbar(a.bar, nwg);

    // ---- P4: gates = ct@W + pe@W + gh + bias; LSTM update ----
    for (int it = wgid; it < 64; it += nwg) {
      const int j0 = it*16;
      const unsigned short* Whi = a.w3h + (size_t)(w*DH + j0)*1344;
      const unsigned short* Wlo = a.w3l + (size_t)(w*DH + j0)*1344;
      f32x4 acc[4];
#pragma unroll
      for (int m=0;m<4;++m) acc[m] = 0.f;
      mm16<1024>(acc, a.ctH, DH, Whi, 1344, lane);
      mm16<1024>(acc, a.ctH, DH, Wlo, 1344, lane);
      mm16<1024>(acc, a.ctL, DH, Whi, 1344, lane);
      const unsigned short* pe = a.pe + (size_t)t*NB*EMBP;
      mm16<EMBP>(acc, pe, EMBP, Whi + 1024, 1344, lane);
      mm16<EMBP>(acc, pe, EMBP, Wlo + 1024, 1344, lane);
#pragma unroll
      for (int m=0;m<4;++m)
#pragma unroll
        for (int e=0;e<4;++e) sm4[w][m*16 + q4*4 + e][r] = acc[m][e];
      __syncthreads();
      for (int p = tid; p < 1024; p += 256) {
        int b = p >> 4, jj = p & 15, j = j0 + jj;
        float gi = sm4[0][b][jj] + a.gh[(size_t)b*4096 + 0*DH + j] + a.db4[0*DH + j];
        float gf = sm4[1][b][jj] + a.gh[(size_t)b*4096 + 1*DH + j] + a.db4[1*DH + j];
        float gg = sm4[2][b][jj] + a.gh[(size_t)b*4096 + 2*DH + j] + a.db4[2*DH + j];
        float go = sm4[3][b][jj] + a.gh[(size_t)b*4096 + 3*DH + j] + a.db4[3*DH + j];
        float co = a.dc[b*DH + j];
        float cn = sigm(gf)*co + sigm(gi)*tanhf(gg);
        float hn = sigm(go)*tanhf(cn);
        a.dc[b*DH + j] = cn;
        unsigned short hb = f2b(hn);
        a.dhH[b*DH + j] = hb;
        a.dhL[b*DH + j] = f2b(hn - b2f(hb));
        a.hdec[((size_t)t*NB + b)*DH + j] = hb;
      }
      __syncthreads();
    }
    gbar(a.bar, nwg);
  }
}

// ---------------- in-place log-softmax over vocab rows ----------------
__global__ __launch_bounds__(256) void lsm(float* __restrict__ out)
{
  const int row = NB + blockIdx.x;  // rows 64..3199
  float* p = out + (size_t)row*GV;
  const int tid = threadIdx.x;
  __shared__ float red[4], red2[4];
  float mx = -1e30f;
  for (int i = tid; i < GV; i += 256) mx = fmaxf(mx, p[i]);
  for (int off=32; off; off>>=1) mx = fmaxf(mx, __shfl_down(mx, off));
  if ((tid & 63) == 0) red[tid>>6] = mx;
  __syncthreads();
  mx = fmaxf(fmaxf(red[0],red[1]), fmaxf(red[2],red[3]));
  float sm = 0.f;
  for (int i = tid; i < GV; i += 256) sm += expf(p[i] - mx);
  for (int off=32; off; off>>=1) sm += __shfl_down(sm, off);
  if ((tid & 63) == 0) red2[tid>>6] = sm;
  __syncthreads();
  sm = red2[0]+red2[1]+red2[2]+red2[3];
  float lse = mx + logf(sm);
  for (int i = tid; i < GV; i += 256) p[i] -= lse;
}

// ---------------- host ----------------
extern "C" void kernel_launch(void* const* d_in, const int* in_sizes, int n_in,
                              void* d_out, int out_size, void* d_ws, size_t ws_size,
                              hipStream_t stream)
{
  const int*   src  = (const int*)d_in[0];
  const int*   trg  = (const int*)d_in[1];
  const float* WihF = (const float*)d_in[2];
  const float* WhhF = (const float*)d_in[3];
  const float* bihF = (const float*)d_in[4];
  const float* bhhF = (const float*)d_in[5];
  const float* WihR = (const float*)d_in[6];
  const float* WhhR = (const float*)d_in[7];
  const float* bihR = (const float*)d_in[8];
  const float* bhhR = (const float*)d_in[9];
  const float* dWih = (const float*)d_in[10];
  const float* dWhh = (const float*)d_in[11];
  const float* dbih = (const float*)d_in[12];
  const float* dbhh = (const float*)d_in[13];
  const float* eemb = (const float*)d_in[14];
  const float* demb = (const float*)d_in[15];
  const float* wi   = (const float*)d_in[16];
  const float* wo   = (const float*)d_in[17];
  const float* genw = (const float*)d_in[18];
  const float* genb = (const float*)d_in[19];
  float* out = (float*)d_out;

  char* ws = (char*)d_ws;
  size_t off = 0;
  auto alloc = [&](size_t bytes)->char* {
    char* p = ws + off; off = (off + bytes + 255) & ~(size_t)255; return p;
  };
  unsigned short* x_bf    = (unsigned short*)alloc((size_t)TSRC*NB*EMBP*2);
  unsigned short* xrev_bf = (unsigned short*)alloc((size_t)TSRC*NB*EMBP*2);
  unsigned short* pe_bf   = (unsigned short*)alloc((size_t)TDEC*NB*EMBP*2);
  unsigned short* wihF_b  = (unsigned short*)alloc((size_t)2048*EMBP*2);
  unsigned short* wihR_b  = (unsigned short*)alloc((size_t)2048*EMBP*2);
  unsigned short* whhF_h  = (unsigned short*)alloc((size_t)2048*EH*2);
  unsigned short* whhF_l  = (unsigned short*)alloc((size_t)2048*EH*2);
  unsigned short* whhR_h  = (unsigned short*)alloc((size_t)2048*EH*2);
  unsigned short* whhR_l  = (unsigned short*)alloc((size_t)2048*EH*2);
  unsigned short* wm1_h   = (unsigned short*)alloc((size_t)5120*DH*2);
  unsigned short* wm1_l   = (unsigned short*)alloc((size_t)5120*DH*2);
  unsigned short* wo_h    = (unsigned short*)alloc((size_t)DH*2048*2);
  unsigned short* wo_l    = (unsigned short*)alloc((size_t)DH*2048*2);
  unsigned short* wih3_h  = (unsigned short*)alloc((size_t)4096*1344*2);
  unsigned short* wih3_l  = (unsigned short*)alloc((size_t)4096*1344*2);
  unsigned short* genw_b  = (unsigned short*)alloc((size_t)GVP*DH*2);
  float* b4f   = (float*)alloc(2048*4);
  float* b4r   = (float*)alloc(2048*4);
  float* db4   = (float*)alloc(4096*4);
  float* xp_f  = (float*)alloc((size_t)TSRC*NB*2048*4);
  float* xp_r  = (float*)alloc((size_t)TSRC*NB*2048*4);
  float* enc_out = (float*)alloc((size_t)TSRC*NB*DH*4);
  unsigned short* hH = (unsigned short*)alloc((size_t)4*NB*EH*2);
  unsigned short* hL = (unsigned short*)alloc((size_t)4*NB*EH*2);
  float* cf = (float*)alloc((size_t)NB*EH*4);
  float* cr = (float*)alloc((size_t)NB*EH*4);
  unsigned short* dhH = (unsigned short*)alloc((size_t)NB*DH*2);
  unsigned short* dhL = (unsigned short*)alloc((size_t)NB*DH*2);
  float* dc = (float*)alloc((size_t)NB*DH*4);
  float* qb = (float*)alloc((size_t)NB*DH*4);
  float* gh = (float*)alloc((size_t)NB*4096*4);
  unsigned short* stH = (unsigned short*)alloc((size_t)NB*DH*2);
  unsigned short* stL = (unsigned short*)alloc((size_t)NB*DH*2);
  unsigned short* ctH = (unsigned short*)alloc((size_t)NB*DH*2);
  unsigned short* ctL = (unsigned short*)alloc((size_t)NB*DH*2);
  unsigned short* hdec = (unsigned short*)alloc((size_t)3200*DH*2);
  int* bar = (int*)alloc(256);
  (void)in_sizes; (void)n_in; (void)out_size; (void)ws_size;

  // --- init / zero state (every call: graph replays don't re-poison) ---
  hipMemsetAsync(hH, 0, (size_t)4*NB*EH*2, stream);
  hipMemsetAsync(hL, 0, (size_t)4*NB*EH*2, stream);
  hipMemsetAsync(cf, 0, (size_t)NB*EH*4, stream);
  hipMemsetAsync(cr, 0, (size_t)NB*EH*4, stream);
  hipMemsetAsync(hdec + (size_t)3136*DH, 0, (size_t)64*DH*2, stream);
  hipMemsetAsync(genw_b + (size_t)GV*DH, 0, (size_t)(GVP-GV)*DH*2, stream);
  hipMemsetAsync(out, 0, (size_t)NB*GV*4, stream);   // timestep 0 = zeros
  hipMemsetAsync(bar, 0, 256, stream);

  auto cgrid = [](size_t n){ return dim3((unsigned)((n + 255)/256)); };

  // --- weight conversion ---
  cvt_pad<<<cgrid((size_t)2048*EMBP),256,0,stream>>>(WihF, wihF_b, 2048, EMBD, EMBP);
  cvt_pad<<<cgrid((size_t)2048*EMBP),256,0,stream>>>(WihR, wihR_b, 2048, EMBD, EMBP);
  cvt_split<<<cgrid((size_t)2048*EH),256,0,stream>>>(WhhF, whhF_h, whhF_l, 2048, EH, EH);
  cvt_split<<<cgrid((size_t)2048*EH),256,0,stream>>>(WhhR, whhR_h, whhR_l, 2048, EH, EH);
  cvt_split<<<cgrid((size_t)1024*DH),256,0,stream>>>(wi, wm1_h, wm1_l, 1024, DH, DH);
  cvt_split<<<cgrid((size_t)4096*DH),256,0,stream>>>(dWhh, wm1_h + (size_t)1024*DH, wm1_l + (size_t)1024*DH, 4096, DH, DH);
  cvt_split<<<cgrid((size_t)DH*2048),256,0,stream>>>(wo, wo_h, wo_l, DH, 2048, 2048);
  cvt_split<<<cgrid((size_t)4096*1344),256,0,stream>>>(dWih, wih3_h, wih3_l, 4096, 1324, 1344);
  cvt_pad<<<cgrid((size_t)GV*DH),256,0,stream>>>(genw, genw_b, GV, DH, DH);
  addb<<<cgrid(2048),256,0,stream>>>(bihF, bhhF, b4f, 2048);
  addb<<<cgrid(2048),256,0,stream>>>(bihR, bhhR, b4r, 2048);
  addb<<<cgrid(4096),256,0,stream>>>(dbih, dbhh, db4, 4096);
  k_embed<<<cgrid((size_t)(TSRC+TDEC)*NB*EMBP),256,0,stream>>>(src, trg, eemb, demb, x_bf, xrev_bf, pe_bf);

  // --- encoder input projections (bias folded in) ---
  gemm128<<<dim3(16,25),256,0,stream>>>(x_bf,    EMBP, wihF_b, EMBP, b4f, xp_f, 2048, EMBP, 3200, 2048, 0);
  gemm128<<<dim3(16,25),256,0,stream>>>(xrev_bf, EMBP, wihR_b, EMBP, b4r, xp_r, 2048, EMBP, 3200, 2048, 0);

  // --- persistent sequential kernel: encoder + decoder ---
  SA sa;
  sa.whhFh = whhF_h; sa.whhFl = whhF_l; sa.whhRh = whhR_h; sa.whhRl = whhR_l;
  sa.wm1h = wm1_h; sa.wm1l = wm1_l;
  sa.woh = wo_h; sa.wol = wo_l;
  sa.w3h = wih3_h; sa.w3l = wih3_l;
  sa.pe = pe_bf;
  sa.xpF = xp_f; sa.xpR = xp_r;
  sa.db4 = db4;
  sa.hH = hH; sa.hL = hL;
  sa.cF = cf; sa.cR = cr;
  sa.enc_out = enc_out;
  sa.dhH = dhH; sa.dhL = dhL; sa.dc = dc;
  sa.q = qb; sa.gh = gh;
  sa.stH = stH; sa.stL = stL; sa.ctH = ctH; sa.ctL = ctL;
  sa.hdec = hdec;
  sa.bar = bar;
  seq_kernel<<<dim3(GRID), 256, 0, stream>>>(sa);

  // --- generator: logits into d_out rows 64.. (t+1 shift), then log-softmax ---
  gemm128<<<dim3(GVP/128,25),256,0,stream>>>(hdec, DH, genw_b, DH, genb, out, GV, DH, 3136, GV, NB);
  lsm<<<3136,256,0,stream>>>(out);
}

// Round 4
// 10665.584 us; speedup vs baseline: 3.8060x; 3.8060x over previous
//
#include <hip/hip_runtime.h>
#include <cstdint>
#include <cmath>

// ---------------- dims ----------------
#define NB    64      // batch
#define EMBD  300
#define EMBP  320     // padded K for embedding-side GEMMs
#define EH    512     // encoder hidden
#define DH    1024    // decoder hidden
#define GV    23262   // target vocab
#define GVP   23296   // padded to 182*128
#define TSRC  50
#define TDEC  49      // decoder steps
#define GRID  160     // persistent kernel workgroups (<=256 CUs -> co-resident)

typedef __attribute__((ext_vector_type(8))) short bf16x8;
typedef __attribute__((ext_vector_type(4))) float f32x4;

__device__ __forceinline__ unsigned short f2b(float f){
  union { float f; uint32_t u; } v; v.f = f;
  uint32_t u = (v.u + 0x7fffu + ((v.u >> 16) & 1u)) >> 16;
  return (unsigned short)u;
}
__device__ __forceinline__ float b2f(unsigned short h){
  union { uint32_t u; float f; } v; v.u = ((uint32_t)h) << 16;
  return v.f;
}
__device__ __forceinline__ float sigm(float x){ return 1.f/(1.f+expf(-x)); }

// Split-precision 64x16 tile: acc += Ah@Whi^T + Al@Whi^T + Ah@Wlo^T
// B (Whi/Wlo) loaded ONCE per k-slice and reused -> weight stream = hi+lo (2x single).
// a-frag lane l: A[(l&15)+16*m][k+(l>>4)*8+e]; b-frag lane l: W[(l&15)][k+(l>>4)*8+e]
// d lane l reg e: D[m*16+(l>>4)*4+e][l&15]
template<int K>
__device__ __forceinline__ void mm16_split(f32x4 (&acc)[4],
    const unsigned short* __restrict__ Ah, const unsigned short* __restrict__ Al, int lda,
    const unsigned short* __restrict__ Whi, const unsigned short* __restrict__ Wlo, int ldw,
    int lane)
{
  const int r = lane & 15, q = lane >> 4;
  const unsigned short* ah0 = Ah + r*lda + q*8;
  const unsigned short* al0 = Al + r*lda + q*8;
  const unsigned short* bh0 = Whi + (size_t)r*ldw + q*8;
  const unsigned short* bl0 = Wlo + (size_t)r*ldw + q*8;
#pragma unroll 4
  for (int k = 0; k < K; k += 32) {
    bf16x8 bh = *(const bf16x8*)(bh0 + k);
    bf16x8 bl = *(const bf16x8*)(bl0 + k);
#pragma unroll
    for (int m = 0; m < 4; ++m) {
      bf16x8 ah = *(const bf16x8*)(ah0 + m*16*lda + k);
      bf16x8 al = *(const bf16x8*)(al0 + m*16*lda + k);
      acc[m] = __builtin_amdgcn_mfma_f32_16x16x32_bf16(ah, bh, acc[m], 0, 0, 0);
      acc[m] = __builtin_amdgcn_mfma_f32_16x16x32_bf16(al, bh, acc[m], 0, 0, 0);
      acc[m] = __builtin_amdgcn_mfma_f32_16x16x32_bf16(ah, bl, acc[m], 0, 0, 0);
    }
  }
}

// ---------------- prep kernels ----------------
__global__ void cvt_pad(const float* __restrict__ src, unsigned short* __restrict__ dst,
                        int rows, int scols, int dcols)
{
  int idx = blockIdx.x*256 + threadIdx.x;
  if (idx >= rows*dcols) return;
  int c = idx % dcols, rr = idx / dcols;
  dst[idx] = (c < scols) ? f2b(src[(size_t)rr*scols + c]) : (unsigned short)0;
}

__global__ void cvt_split(const float* __restrict__ src,
                          unsigned short* __restrict__ hi, unsigned short* __restrict__ lo,
                          int rows, int scols, int dcols)
{
  int idx = blockIdx.x*256 + threadIdx.x;
  if (idx >= rows*dcols) return;
  int c = idx % dcols, rr = idx / dcols;
  float v = (c < scols) ? src[(size_t)rr*scols + c] : 0.f;
  unsigned short h = f2b(v);
  hi[idx] = h;
  lo[idx] = f2b(v - b2f(h));
}

__global__ void addb(const float* __restrict__ a, const float* __restrict__ b,
                     float* __restrict__ o, int n)
{
  int i = blockIdx.x*256 + threadIdx.x;
  if (i < n) o[i] = a[i] + b[i];
}

__global__ void k_embed(const int* __restrict__ src, const int* __restrict__ trg,
                        const float* __restrict__ eemb, const float* __restrict__ demb,
                        unsigned short* __restrict__ x_bf, unsigned short* __restrict__ xrev_bf,
                        unsigned short* __restrict__ pe_bf)
{
  int idx = blockIdx.x*256 + threadIdx.x;
  const int tot1 = TSRC*NB*EMBP;
  const int tot2 = TDEC*NB*EMBP;
  if (idx < tot1) {
    int e = idx % EMBP, rb = idx / EMBP;
    int t = rb >> 6, b = rb & 63;
    float v = 0.f;
    if (e < EMBD) v = eemb[(size_t)src[rb]*EMBD + e];
    unsigned short bv = f2b(v);
    x_bf[idx] = bv;
    xrev_bf[(size_t)((TSRC-1-t)*NB + b)*EMBP + e] = bv;
  } else if (idx < tot1 + tot2) {
    int k = idx - tot1;
    int e = k % EMBP, rb = k / EMBP;
    float v = 0.f;
    if (e < EMBD) v = demb[(size_t)trg[rb]*EMBD + e];
    pe_bf[k] = f2b(v);
  }
}

// ---------------- big tiled GEMM (throughput path: proj + peproj + generator) ----------------
__global__ __launch_bounds__(256) void gemm128(
    const unsigned short* __restrict__ A, int lda,
    const unsigned short* __restrict__ W, int ldw,
    const float* __restrict__ bias,
    float* __restrict__ out, int ldo,
    int K, int mvalid, int nvalid, int rowoff)
{
  __shared__ unsigned short As[128*64];
  __shared__ unsigned short Bs[128*64];
  const int tid = threadIdx.x;
  const int m0 = blockIdx.y*128, n0 = blockIdx.x*128;
  const int w = tid >> 6, lane = tid & 63, r = lane & 15, q = lane >> 4;
  const int mw = (w >> 1)*64, nw = (w & 1)*64;
  f32x4 acc[4][4];
#pragma unroll
  for (int mi=0; mi<4; ++mi)
#pragma unroll
    for (int ni=0; ni<4; ++ni) acc[mi][ni] = 0.f;

  for (int kt = 0; kt < K; kt += 64) {
    bf16x8 ra[4], rb[4];
#pragma unroll
    for (int j = 0; j < 4; ++j) {
      int c = j*256 + tid, row = c >> 3, cc = c & 7;
      ra[j] = *(const bf16x8*)(A + (size_t)(m0+row)*lda + kt + cc*8);
      rb[j] = *(const bf16x8*)(W + (size_t)(n0+row)*ldw + kt + cc*8);
    }
    __syncthreads();
#pragma unroll
    for (int j = 0; j < 4; ++j) {
      int c = j*256 + tid, row = c >> 3, cc = c & 7;
      int sw = cc ^ (row & 7);
      *(bf16x8*)((char*)As + row*128 + (sw<<4)) = ra[j];
      *(bf16x8*)((char*)Bs + row*128 + (sw<<4)) = rb[j];
    }
    __syncthreads();
#pragma unroll
    for (int kk = 0; kk < 64; kk += 32) {
      int ch = (kk >> 3) + q;
      bf16x8 av[4], bv[4];
#pragma unroll
      for (int mi=0; mi<4; ++mi) {
        int row = mw + mi*16 + r;
        av[mi] = *(const bf16x8*)((char*)As + row*128 + ((ch ^ (row&7))<<4));
      }
#pragma unroll
      for (int ni=0; ni<4; ++ni) {
        int row = nw + ni*16 + r;
        bv[ni] = *(const bf16x8*)((char*)Bs + row*128 + ((ch ^ (row&7))<<4));
      }
#pragma unroll
      for (int mi=0; mi<4; ++mi)
#pragma unroll
        for (int ni=0; ni<4; ++ni)
          acc[mi][ni] = __builtin_amdgcn_mfma_f32_16x16x32_bf16(av[mi], bv[ni], acc[mi][ni], 0,0,0);
    }
  }
#pragma unroll
  for (int mi=0; mi<4; ++mi)
#pragma unroll
    for (int ni=0; ni<4; ++ni)
#pragma unroll
      for (int e=0; e<4; ++e) {
        int mrow = m0 + mw + mi*16 + q*4 + e;
        int col  = n0 + nw + ni*16 + r;
        if (mrow < mvalid && col < nvalid)
          out[(size_t)(mrow + rowoff)*ldo + col] = acc[mi][ni][e] + bias[col];
      }
}

// ---------------- persistent sequential kernel (encoder + decoder) ----------------
struct SA {
  const unsigned short *whhFh, *whhFl, *whhRh, *whhRl;    // [2048][512]
  const unsigned short *wm1h, *wm1l;                      // [5120][1024]
  const unsigned short *woh, *wol;                        // [1024][2048]
  const unsigned short *w3h, *w3l;                        // [4096][1344]
  const float *xpF, *xpR;                                 // [50*64][2048] (bias included)
  const float *pp;                                        // [49*64][4096] pe@dWihB + biases
  unsigned short *hH, *hL;                                // [2 dir][2 buf][64][512]
  float *cF, *cR;                                         // [64][512]
  float *enc_out;                                         // [50][64][1024] fp32
  unsigned short *dhH, *dhL;                              // [64][1024]
  float *dc;                                              // [64][1024]
  float *q;                                               // [64][1024]
  float *gh;                                              // [64][4096]
  unsigned short *stH, *stL, *ctH, *ctL;                  // [64][1024]
  unsigned short *hdec;                                   // [3200][1024]
  int *bar;                                               // [cnt, gen]
};

// Lightweight grid barrier: release-add, RELAXED spin (+sleep), one acquire on exit.
// No per-iteration cache invalidation (the round-3 killer).
__device__ __forceinline__ void gbar(int* bar, int nwg)
{
  __syncthreads();
  if (threadIdx.x == 0) {
    int* cnt = bar;
    int* gen = bar + 1;
    int g = __hip_atomic_load(gen, __ATOMIC_RELAXED, __HIP_MEMORY_SCOPE_AGENT);
    int v = __hip_atomic_fetch_add(cnt, 1, __ATOMIC_ACQ_REL, __HIP_MEMORY_SCOPE_AGENT);
    if (v == nwg - 1) {
      __hip_atomic_store(cnt, 0, __ATOMIC_RELAXED, __HIP_MEMORY_SCOPE_AGENT);
      __hip_atomic_store(gen, g + 1, __ATOMIC_RELEASE, __HIP_MEMORY_SCOPE_AGENT);
    } else {
      while (__hip_atomic_load(gen, __ATOMIC_RELAXED, __HIP_MEMORY_SCOPE_AGENT) == g)
        __builtin_amdgcn_s_sleep(4);
      (void)__hip_atomic_load(gen, __ATOMIC_ACQUIRE, __HIP_MEMORY_SCOPE_AGENT);
    }
  }
  __syncthreads();
}

__global__ __launch_bounds__(256, 1) void seq_kernel(SA a)
{
  const int tid = threadIdx.x, w = tid >> 6, lane = tid & 63;
  const int nwg = gridDim.x, wgid = blockIdx.x;
  const int r = lane & 15, q4 = lane >> 4;
  __shared__ float sm4[4][64][16];
  __shared__ float qs[1024];
  __shared__ float sc[56];

  // ================= encoder: 50 steps =================
  for (int t = 0; t < TSRC; ++t) {
    const int cur = t & 1;
    for (int it = wgid; it < 64; it += nwg) {
      const int dir = it >> 5, j0 = (it & 31) << 4;
      const unsigned short* Whi = (dir ? a.whhRh : a.whhFh) + (size_t)(w*EH + j0)*EH;
      const unsigned short* Wlo = (dir ? a.whhRl : a.whhFl) + (size_t)(w*EH + j0)*EH;
      const unsigned short* Hh = a.hH + (size_t)(dir*2 + cur)*NB*EH;
      const unsigned short* Hl = a.hL + (size_t)(dir*2 + cur)*NB*EH;
      f32x4 acc[4];
#pragma unroll
      for (int m=0;m<4;++m) acc[m] = 0.f;
      mm16_split<EH>(acc, Hh, Hl, EH, Whi, Wlo, EH, lane);
#pragma unroll
      for (int m=0;m<4;++m)
#pragma unroll
        for (int e=0;e<4;++e) sm4[w][m*16 + q4*4 + e][r] = acc[m][e];
      __syncthreads();
      const float* xp = (dir ? a.xpR : a.xpF) + (size_t)t*NB*2048;
      float* C = dir ? a.cR : a.cF;
      unsigned short* HoH = a.hH + (size_t)(dir*2 + (cur^1))*NB*EH;
      unsigned short* HoL = a.hL + (size_t)(dir*2 + (cur^1))*NB*EH;
      const int erow = dir ? (TSRC-1 - t) : t;
      for (int p = tid; p < 1024; p += 256) {
        int b = p >> 4, jj = p & 15, j = j0 + jj;
        float gi = sm4[0][b][jj] + xp[b*2048 + 0*EH + j];
        float gf = sm4[1][b][jj] + xp[b*2048 + 1*EH + j];
        float gg = sm4[2][b][jj] + xp[b*2048 + 2*EH + j];
        float go = sm4[3][b][jj] + xp[b*2048 + 3*EH + j];
        float co = C[b*EH + j];
        float cn = sigm(gf)*co + sigm(gi)*tanhf(gg);
        float hn = sigm(go)*tanhf(cn);
        C[b*EH + j] = cn;
        unsigned short hb = f2b(hn);
        unsigned short lb = f2b(hn - b2f(hb));
        HoH[b*EH + j] = hb;
        HoL[b*EH + j] = lb;
        a.enc_out[((size_t)erow*NB + b)*DH + dir*EH + j] = hn;
        if (t == TSRC-1) {
          a.dhH[b*DH + 2*j + dir] = hb;
          a.dhL[b*DH + 2*j + dir] = lb;
          a.dc [b*DH + 2*j + dir] = cn;
        }
      }
      __syncthreads();
    }
    gbar(a.bar, nwg);
  }

  // ================= decoder: 49 steps =================
  for (int t = 0; t < TDEC; ++t) {
    // ---- P1: q|gh = h @ [wi ; dWhh]^T (split, K halves across wave pairs) ----
    for (int it = wgid; it < 160; it += nwg) {
      const int kh = w & 1, col0 = it*32 + (w >> 1)*16;
      const unsigned short* Whi = a.wm1h + (size_t)col0*DH + kh*512;
      const unsigned short* Wlo = a.wm1l + (size_t)col0*DH + kh*512;
      f32x4 acc[4];
#pragma unroll
      for (int m=0;m<4;++m) acc[m] = 0.f;
      mm16_split<512>(acc, a.dhH + kh*512, a.dhL + kh*512, DH, Whi, Wlo, DH, lane);
#pragma unroll
      for (int m=0;m<4;++m)
#pragma unroll
        for (int e=0;e<4;++e) sm4[w][m*16 + q4*4 + e][r] = acc[m][e];
      __syncthreads();
      for (int p = tid; p < 2048; p += 256) {
        int b = p >> 5, cc = p & 31;
        float v = sm4[(cc>>4)*2][b][cc&15] + sm4[(cc>>4)*2 + 1][b][cc&15];
        int C = it*32 + cc;
        if (C < 1024) a.q[b*DH + C] = v;
        else          a.gh[(size_t)b*4096 + C - 1024] = v;
      }
      __syncthreads();
    }
    gbar(a.bar, nwg);

    // ---- P2: attention per batch element ----
    for (int it = wgid; it < NB; it += nwg) {
      const int b = it;
      for (int i = tid; i < 1024; i += 256) qs[i] = a.q[b*DH + i];
      __syncthreads();
      for (int tt = w; tt < TSRC; tt += 4) {
        const float* er = a.enc_out + ((size_t)tt*NB + b)*DH + lane*16;
        const float* qq = qs + lane*16;
        float s = 0.f;
#pragma unroll
        for (int ii=0; ii<16; ++ii) s += er[ii]*qq[ii];
#pragma unroll
        for (int o=32; o; o>>=1) s += __shfl_xor(s, o);
        if (lane == 0) sc[tt] = s;
      }
      __syncthreads();
      float mx = -1e30f;
      for (int tt=0; tt<TSRC; ++tt) mx = fmaxf(mx, sc[tt]);
      __syncthreads();
      if (tid < TSRC) sc[tid] = expf(sc[tid] - mx);
      __syncthreads();
      float s50 = 0.f;
      for (int tt=0; tt<TSRC; ++tt) s50 += sc[tt];
      const float inv = 1.f/s50;
      const int c0 = tid*4;
      float a0=0.f, a1=0.f, a2=0.f, a3=0.f;
      for (int tt=0; tt<TSRC; ++tt) {
        float wt = sc[tt];
        const float* er = a.enc_out + ((size_t)tt*NB + b)*DH + c0;
        a0 += wt*er[0]; a1 += wt*er[1]; a2 += wt*er[2]; a3 += wt*er[3];
      }
      float av[4] = {a0*inv, a1*inv, a2*inv, a3*inv};
#pragma unroll
      for (int i=0;i<4;++i) {
        unsigned short hb = f2b(av[i]);
        a.stH[b*DH + c0 + i] = hb;
        a.stL[b*DH + c0 + i] = f2b(av[i] - b2f(hb));
      }
      __syncthreads();
    }
    gbar(a.bar, nwg);

    // ---- P3: ct = tanh([st,h] @ wo^T) (split; st/h halves across wave pairs) ----
    for (int it = wgid; it < 32; it += nwg) {
      const int kh = w & 1, col0 = it*32 + (w >> 1)*16;
      const unsigned short* Whi = a.woh + (size_t)col0*2048 + kh*1024;
      const unsigned short* Wlo = a.wol + (size_t)col0*2048 + kh*1024;
      const unsigned short* Ah = kh ? a.dhH : a.stH;
      const unsigned short* Al = kh ? a.dhL : a.stL;
      f32x4 acc[4];
#pragma unroll
      for (int m=0;m<4;++m) acc[m] = 0.f;
      mm16_split<1024>(acc, Ah, Al, DH, Whi, Wlo, 2048, lane);
#pragma unroll
      for (int m=0;m<4;++m)
#pragma unroll
        for (int e=0;e<4;++e) sm4[w][m*16 + q4*4 + e][r] = acc[m][e];
      __syncthreads();
      for (int p = tid; p < 2048; p += 256) {
        int b = p >> 5, cc = p & 31;
        float v = sm4[(cc>>4)*2][b][cc&15] + sm4[(cc>>4)*2 + 1][b][cc&15];
        float ct = tanhf(v);
        unsigned short hb = f2b(ct);
        int C = it*32 + cc;
        a.ctH[b*DH + C] = hb;
        a.ctL[b*DH + C] = f2b(ct - b2f(hb));
      }
      __syncthreads();
    }
    gbar(a.bar, nwg);

    // ---- P4: gates = ct@W(split) + gh + peproj; LSTM update ----
    for (int it = wgid; it < 64; it += nwg) {
      const int j0 = it*16;
      const unsigned short* Whi = a.w3h + (size_t)(w*DH + j0)*1344;
      const unsigned short* Wlo = a.w3l + (size_t)(w*DH + j0)*1344;
      f32x4 acc[4];
#pragma unroll
      for (int m=0;m<4;++m) acc[m] = 0.f;
      mm16_split<1024>(acc, a.ctH, a.ctL, DH, Whi, Wlo, 1344, lane);
#pragma unroll
      for (int m=0;m<4;++m)
#pragma unroll
        for (int e=0;e<4;++e) sm4[w][m*16 + q4*4 + e][r] = acc[m][e];
      __syncthreads();
      const float* pp = a.pp + (size_t)t*NB*4096;
      for (int p = tid; p < 1024; p += 256) {
        int b = p >> 4, jj = p & 15, j = j0 + jj;
        float gi = sm4[0][b][jj] + a.gh[(size_t)b*4096 + 0*DH + j] + pp[(size_t)b*4096 + 0*DH + j];
        float gf = sm4[1][b][jj] + a.gh[(size_t)b*4096 + 1*DH + j] + pp[(size_t)b*4096 + 1*DH + j];
        float gg = sm4[2][b][jj] + a.gh[(size_t)b*4096 + 2*DH + j] + pp[(size_t)b*4096 + 2*DH + j];
        float go = sm4[3][b][jj] + a.gh[(size_t)b*4096 + 3*DH + j] + pp[(size_t)b*4096 + 3*DH + j];
        float co = a.dc[b*DH + j];
        float cn = sigm(gf)*co + sigm(gi)*tanhf(gg);
        float hn = sigm(go)*tanhf(cn);
        a.dc[b*DH + j] = cn;
        unsigned short hb = f2b(hn);
        a.dhH[b*DH + j] = hb;
        a.dhL[b*DH + j] = f2b(hn - b2f(hb));
        a.hdec[((size_t)t*NB + b)*DH + j] = hb;
      }
      __syncthreads();
    }
    gbar(a.bar, nwg);
  }
}

// ---------------- in-place log-softmax over vocab rows ----------------
__global__ __launch_bounds__(256) void lsm(float* __restrict__ out)
{
  const int row = NB + blockIdx.x;  // rows 64..3199
  float* p = out + (size_t)row*GV;
  const int tid = threadIdx.x;
  __shared__ float red[4], red2[4];
  float mx = -1e30f;
  for (int i = tid; i < GV; i += 256) mx = fmaxf(mx, p[i]);
  for (int off=32; off; off>>=1) mx = fmaxf(mx, __shfl_down(mx, off));
  if ((tid & 63) == 0) red[tid>>6] = mx;
  __syncthreads();
  mx = fmaxf(fmaxf(red[0],red[1]), fmaxf(red[2],red[3]));
  float sm = 0.f;
  for (int i = tid; i < GV; i += 256) sm += expf(p[i] - mx);
  for (int off=32; off; off>>=1) sm += __shfl_down(sm, off);
  if ((tid & 63) == 0) red2[tid>>6] = sm;
  __syncthreads();
  sm = red2[0]+red2[1]+red2[2]+red2[3];
  float lse = mx + logf(sm);
  for (int i = tid; i < GV; i += 256) p[i] -= lse;
}

// ---------------- host ----------------
extern "C" void kernel_launch(void* const* d_in, const int* in_sizes, int n_in,
                              void* d_out, int out_size, void* d_ws, size_t ws_size,
                              hipStream_t stream)
{
  const int*   src  = (const int*)d_in[0];
  const int*   trg  = (const int*)d_in[1];
  const float* WihF = (const float*)d_in[2];
  const float* WhhF = (const float*)d_in[3];
  const float* bihF = (const float*)d_in[4];
  const float* bhhF = (const float*)d_in[5];
  const float* WihR = (const float*)d_in[6];
  const float* WhhR = (const float*)d_in[7];
  const float* bihR = (const float*)d_in[8];
  const float* bhhR = (const float*)d_in[9];
  const float* dWih = (const float*)d_in[10];
  const float* dWhh = (const float*)d_in[11];
  const float* dbih = (const float*)d_in[12];
  const float* dbhh = (const float*)d_in[13];
  const float* eemb = (const float*)d_in[14];
  const float* demb = (const float*)d_in[15];
  const float* wi   = (const float*)d_in[16];
  const float* wo   = (const float*)d_in[17];
  const float* genw = (const float*)d_in[18];
  const float* genb = (const float*)d_in[19];
  float* out = (float*)d_out;

  char* ws = (char*)d_ws;
  size_t off = 0;
  auto alloc = [&](size_t bytes)->char* {
    char* p = ws + off; off = (off + bytes + 255) & ~(size_t)255; return p;
  };
  unsigned short* x_bf    = (unsigned short*)alloc((size_t)TSRC*NB*EMBP*2);
  unsigned short* xrev_bf = (unsigned short*)alloc((size_t)TSRC*NB*EMBP*2);
  unsigned short* pe_bf   = (unsigned short*)alloc((size_t)TDEC*NB*EMBP*2);
  unsigned short* wihF_b  = (unsigned short*)alloc((size_t)2048*EMBP*2);
  unsigned short* wihR_b  = (unsigned short*)alloc((size_t)2048*EMBP*2);
  unsigned short* whhF_h  = (unsigned short*)alloc((size_t)2048*EH*2);
  unsigned short* whhF_l  = (unsigned short*)alloc((size_t)2048*EH*2);
  unsigned short* whhR_h  = (unsigned short*)alloc((size_t)2048*EH*2);
  unsigned short* whhR_l  = (unsigned short*)alloc((size_t)2048*EH*2);
  unsigned short* wm1_h   = (unsigned short*)alloc((size_t)5120*DH*2);
  unsigned short* wm1_l   = (unsigned short*)alloc((size_t)5120*DH*2);
  unsigned short* wo_h    = (unsigned short*)alloc((size_t)DH*2048*2);
  unsigned short* wo_l    = (unsigned short*)alloc((size_t)DH*2048*2);
  unsigned short* wih3_h  = (unsigned short*)alloc((size_t)4096*1344*2);
  unsigned short* wih3_l  = (unsigned short*)alloc((size_t)4096*1344*2);
  unsigned short* genw_b  = (unsigned short*)alloc((size_t)GVP*DH*2);
  float* b4f   = (float*)alloc(2048*4);
  float* b4r   = (float*)alloc(2048*4);
  float* db4   = (float*)alloc(4096*4);
  float* xp_f  = (float*)alloc((size_t)TSRC*NB*2048*4);
  float* xp_r  = (float*)alloc((size_t)TSRC*NB*2048*4);
  float* peproj = (float*)alloc((size_t)TDEC*NB*4096*4);
  float* enc_out = (float*)alloc((size_t)TSRC*NB*DH*4);
  unsigned short* hH = (unsigned short*)alloc((size_t)4*NB*EH*2);
  unsigned short* hL = (unsigned short*)alloc((size_t)4*NB*EH*2);
  float* cf = (float*)alloc((size_t)NB*EH*4);
  float* cr = (float*)alloc((size_t)NB*EH*4);
  unsigned short* dhH = (unsigned short*)alloc((size_t)NB*DH*2);
  unsigned short* dhL = (unsigned short*)alloc((size_t)NB*DH*2);
  float* dc = (float*)alloc((size_t)NB*DH*4);
  float* qb = (float*)alloc((size_t)NB*DH*4);
  float* gh = (float*)alloc((size_t)NB*4096*4);
  unsigned short* stH = (unsigned short*)alloc((size_t)NB*DH*2);
  unsigned short* stL = (unsigned short*)alloc((size_t)NB*DH*2);
  unsigned short* ctH = (unsigned short*)alloc((size_t)NB*DH*2);
  unsigned short* ctL = (unsigned short*)alloc((size_t)NB*DH*2);
  unsigned short* hdec = (unsigned short*)alloc((size_t)3200*DH*2);
  int* bar = (int*)alloc(256);
  (void)in_sizes; (void)n_in; (void)out_size; (void)ws_size;

  // --- init / zero state (every call: graph replays don't re-poison) ---
  hipMemsetAsync(hH, 0, (size_t)4*NB*EH*2, stream);
  hipMemsetAsync(hL, 0, (size_t)4*NB*EH*2, stream);
  hipMemsetAsync(cf, 0, (size_t)NB*EH*4, stream);
  hipMemsetAsync(cr, 0, (size_t)NB*EH*4, stream);
  hipMemsetAsync(hdec + (size_t)3136*DH, 0, (size_t)64*DH*2, stream);
  hipMemsetAsync(genw_b + (size_t)GV*DH, 0, (size_t)(GVP-GV)*DH*2, stream);
  hipMemsetAsync(out, 0, (size_t)NB*GV*4, stream);   // timestep 0 = zeros
  hipMemsetAsync(bar, 0, 256, stream);

  auto cgrid = [](size_t n){ return dim3((unsigned)((n + 255)/256)); };

  // --- weight conversion ---
  cvt_pad<<<cgrid((size_t)2048*EMBP),256,0,stream>>>(WihF, wihF_b, 2048, EMBD, EMBP);
  cvt_pad<<<cgrid((size_t)2048*EMBP),256,0,stream>>>(WihR, wihR_b, 2048, EMBD, EMBP);
  cvt_split<<<cgrid((size_t)2048*EH),256,0,stream>>>(WhhF, whhF_h, whhF_l, 2048, EH, EH);
  cvt_split<<<cgrid((size_t)2048*EH),256,0,stream>>>(WhhR, whhR_h, whhR_l, 2048, EH, EH);
  cvt_split<<<cgrid((size_t)1024*DH),256,0,stream>>>(wi, wm1_h, wm1_l, 1024, DH, DH);
  cvt_split<<<cgrid((size_t)4096*DH),256,0,stream>>>(dWhh, wm1_h + (size_t)1024*DH, wm1_l + (size_t)1024*DH, 4096, DH, DH);
  cvt_split<<<cgrid((size_t)DH*2048),256,0,stream>>>(wo, wo_h, wo_l, DH, 2048, 2048);
  cvt_split<<<cgrid((size_t)4096*1344),256,0,stream>>>(dWih, wih3_h, wih3_l, 4096, 1324, 1344);
  cvt_pad<<<cgrid((size_t)GV*DH),256,0,stream>>>(genw, genw_b, GV, DH, DH);
  addb<<<cgrid(2048),256,0,stream>>>(bihF, bhhF, b4f, 2048);
  addb<<<cgrid(2048),256,0,stream>>>(bihR, bhhR, b4r, 2048);
  addb<<<cgrid(4096),256,0,stream>>>(dbih, dbhh, db4, 4096);
  k_embed<<<cgrid((size_t)(TSRC+TDEC)*NB*EMBP),256,0,stream>>>(src, trg, eemb, demb, x_bf, xrev_bf, pe_bf);

  // --- encoder input projections (bias folded in) + pe projection for decoder ---
  gemm128<<<dim3(16,25),256,0,stream>>>(x_bf,    EMBP, wihF_b, EMBP, b4f, xp_f, 2048, EMBP, 3200, 2048, 0);
  gemm128<<<dim3(16,25),256,0,stream>>>(xrev_bf, EMBP, wihR_b, EMBP, b4r, xp_r, 2048, EMBP, 3200, 2048, 0);
  gemm128<<<dim3(32,25),256,0,stream>>>(pe_bf, EMBP, wih3_h + 1024, 1344, db4, peproj, 4096, EMBP, 3136, 4096, 0);

  // --- persistent sequential kernel: encoder + decoder ---
  SA sa;
  sa.whhFh = whhF_h; sa.whhFl = whhF_l; sa.whhRh = whhR_h; sa.whhRl = whhR_l;
  sa.wm1h = wm1_h; sa.wm1l = wm1_l;
  sa.woh = wo_h; sa.wol = wo_l;
  sa.w3h = wih3_h; sa.w3l = wih3_l;
  sa.xpF = xp_f; sa.xpR = xp_r;
  sa.pp = peproj;
  sa.hH = hH; sa.hL = hL;
  sa.cF = cf; sa.cR = cr;
  sa.enc_out = enc_out;
  sa.dhH = dhH; sa.dhL = dhL; sa.dc = dc;
  sa.q = qb; sa.gh = gh;
  sa.stH = stH; sa.stL = stL; sa.ctH = ctH; sa.ctL = ctL;
  sa.hdec = hdec;
  sa.bar = bar;
  seq_kernel<<<dim3(GRID), 256, 0, stream>>>(sa);

  // --- generator: logits into d_out rows 64.. (t+1 shift), then log-softmax ---
  gemm128<<<dim3(GVP/128,25),256,0,stream>>>(hdec, DH, genw_b, DH, genb, out, GV, DH, 3136, GV, NB);
  lsm<<<3136,256,0,stream>>>(out);
}

// Round 5
// 7206.657 us; speedup vs baseline: 5.6327x; 1.4800x over previous
//
#include <hip/hip_runtime.h>
#include <cstdint>
#include <cmath>

// ---------------- dims ----------------
#define NB    64      // batch
#define EMBD  300
#define EMBP  320     // padded K for embedding-side GEMMs
#define EH    512     // encoder hidden
#define DH    1024    // decoder hidden
#define GV    23262   // target vocab
#define GVP   23296   // padded to 182*128
#define TSRC  50
#define TDEC  49      // decoder steps
#define GRID  160     // persistent kernel workgroups (<=256 CUs -> co-resident)

typedef __attribute__((ext_vector_type(8))) _Float16 f16x8;
typedef __attribute__((ext_vector_type(4))) float f32x4;

__device__ __forceinline__ float sigm(float x){ return 1.f/(1.f+expf(-x)); }

// 64x16 tile: acc += A[64][K](f16) @ W-rows[16][K](f16)^T, fp32 accum.
// Two-phase per 8-slice stage: issue all 40 loads, then 32 MFMAs -> deep VMEM pipeline.
// a-frag lane l: A[(l&15)+16*m][k+(l>>4)*8+e]; b-frag lane l: W[(l&15)][k+(l>>4)*8+e]
// d lane l reg e: D[m*16+(l>>4)*4+e][l&15]   (layout validated rounds 2-4)
template<int K>
__device__ __forceinline__ void mm16h(f32x4 (&acc)[4],
    const _Float16* __restrict__ A, int lda,
    const _Float16* __restrict__ W, int ldw, int lane)
{
  const int r = lane & 15, q = lane >> 4;
  const _Float16* a0 = A + r*lda + q*8;
  const _Float16* b0 = W + (size_t)r*ldw + q*8;
  constexpr int UN = 8;   // 8 k-slices (256 elems) per stage
#pragma unroll
  for (int k0 = 0; k0 < K; k0 += 32*UN) {
    f16x8 bv[UN], av[UN][4];
#pragma unroll
    for (int u = 0; u < UN; ++u) {
      bv[u] = *(const f16x8*)(b0 + k0 + u*32);
#pragma unroll
      for (int m = 0; m < 4; ++m)
        av[u][m] = *(const f16x8*)(a0 + m*16*lda + k0 + u*32);
    }
#pragma unroll
    for (int u = 0; u < UN; ++u)
#pragma unroll
      for (int m = 0; m < 4; ++m)
        acc[m] = __builtin_amdgcn_mfma_f32_16x16x32_f16(av[u][m], bv[u], acc[m], 0, 0, 0);
  }
}

// ---------------- prep kernels ----------------
__global__ void cvt16(const float* __restrict__ src, _Float16* __restrict__ dst,
                      int rows, int scols, int dcols)
{
  int idx = blockIdx.x*256 + threadIdx.x;
  if (idx >= rows*dcols) return;
  int c = idx % dcols, rr = idx / dcols;
  dst[idx] = (c < scols) ? (_Float16)src[(size_t)rr*scols + c] : (_Float16)0.f;
}

__global__ void addb(const float* __restrict__ a, const float* __restrict__ b,
                     float* __restrict__ o, int n)
{
  int i = blockIdx.x*256 + threadIdx.x;
  if (i < n) o[i] = a[i] + b[i];
}

__global__ void k_embed(const int* __restrict__ src, const int* __restrict__ trg,
                        const float* __restrict__ eemb, const float* __restrict__ demb,
                        _Float16* __restrict__ x_h, _Float16* __restrict__ xrev_h,
                        _Float16* __restrict__ pe_h)
{
  int idx = blockIdx.x*256 + threadIdx.x;
  const int tot1 = TSRC*NB*EMBP;
  const int tot2 = TDEC*NB*EMBP;
  if (idx < tot1) {
    int e = idx % EMBP, rb = idx / EMBP;
    int t = rb >> 6, b = rb & 63;
    float v = 0.f;
    if (e < EMBD) v = eemb[(size_t)src[rb]*EMBD + e];
    _Float16 hv = (_Float16)v;
    x_h[idx] = hv;
    xrev_h[(size_t)((TSRC-1-t)*NB + b)*EMBP + e] = hv;
  } else if (idx < tot1 + tot2) {
    int k = idx - tot1;
    int e = k % EMBP, rb = k / EMBP;
    float v = 0.f;
    if (e < EMBD) v = demb[(size_t)trg[rb]*EMBD + e];
    pe_h[k] = (_Float16)v;
  }
}

// ---------------- big tiled GEMM (throughput path: proj + peproj + generator), fp16 ----------------
__global__ __launch_bounds__(256) void gemm128(
    const _Float16* __restrict__ A, int lda,
    const _Float16* __restrict__ W, int ldw,
    const float* __restrict__ bias,
    float* __restrict__ out, int ldo,
    int K, int mvalid, int nvalid, int rowoff)
{
  __shared__ _Float16 As[128*64];
  __shared__ _Float16 Bs[128*64];
  const int tid = threadIdx.x;
  const int m0 = blockIdx.y*128, n0 = blockIdx.x*128;
  const int w = tid >> 6, lane = tid & 63, r = lane & 15, q = lane >> 4;
  const int mw = (w >> 1)*64, nw = (w & 1)*64;
  f32x4 acc[4][4];
#pragma unroll
  for (int mi=0; mi<4; ++mi)
#pragma unroll
    for (int ni=0; ni<4; ++ni) acc[mi][ni] = 0.f;

  for (int kt = 0; kt < K; kt += 64) {
    f16x8 ra[4], rb[4];
#pragma unroll
    for (int j = 0; j < 4; ++j) {
      int c = j*256 + tid, row = c >> 3, cc = c & 7;
      ra[j] = *(const f16x8*)(A + (size_t)(m0+row)*lda + kt + cc*8);
      rb[j] = *(const f16x8*)(W + (size_t)(n0+row)*ldw + kt + cc*8);
    }
    __syncthreads();
#pragma unroll
    for (int j = 0; j < 4; ++j) {
      int c = j*256 + tid, row = c >> 3, cc = c & 7;
      int sw = cc ^ (row & 7);
      *(f16x8*)((char*)As + row*128 + (sw<<4)) = ra[j];
      *(f16x8*)((char*)Bs + row*128 + (sw<<4)) = rb[j];
    }
    __syncthreads();
#pragma unroll
    for (int kk = 0; kk < 64; kk += 32) {
      int ch = (kk >> 3) + q;
      f16x8 av[4], bv[4];
#pragma unroll
      for (int mi=0; mi<4; ++mi) {
        int row = mw + mi*16 + r;
        av[mi] = *(const f16x8*)((char*)As + row*128 + ((ch ^ (row&7))<<4));
      }
#pragma unroll
      for (int ni=0; ni<4; ++ni) {
        int row = nw + ni*16 + r;
        bv[ni] = *(const f16x8*)((char*)Bs + row*128 + ((ch ^ (row&7))<<4));
      }
#pragma unroll
      for (int mi=0; mi<4; ++mi)
#pragma unroll
        for (int ni=0; ni<4; ++ni)
          acc[mi][ni] = __builtin_amdgcn_mfma_f32_16x16x32_f16(av[mi], bv[ni], acc[mi][ni], 0,0,0);
    }
  }
#pragma unroll
  for (int mi=0; mi<4; ++mi)
#pragma unroll
    for (int ni=0; ni<4; ++ni)
#pragma unroll
      for (int e=0; e<4; ++e) {
        int mrow = m0 + mw + mi*16 + q*4 + e;
        int col  = n0 + nw + ni*16 + r;
        if (mrow < mvalid && col < nvalid)
          out[(size_t)(mrow + rowoff)*ldo + col] = acc[mi][ni][e] + bias[col];
      }
}

// ---------------- persistent sequential kernel (encoder + decoder) ----------------
struct SA {
  const _Float16 *whhF, *whhR;       // [2048][512]
  const _Float16 *wm1;               // [5120][1024]
  const _Float16 *wo;                // [1024][2048]
  const _Float16 *w3;                // [4096][1344]
  const float *xpF, *xpR;            // [50*64][2048] (bias included)
  const float *pp;                   // [49*64][4096] pe@dWihB + biases
  _Float16 *h;                       // [2 dir][2 buf][64][512]
  float *cF, *cR;                    // [64][512]
  _Float16 *enc_out;                 // [50][64][1024]
  _Float16 *dh;                      // [64][1024]
  float *dc;                         // [64][1024]
  float *q;                          // [64][1024]
  float *gh;                         // [64][4096]
  _Float16 *st, *ct;                 // [64][1024]
  _Float16 *hdec;                    // [3200][1024]
  int *bar;                          // [cnt, gen]
};

// Lightweight grid barrier: release-add, RELAXED spin (+sleep), one acquire on exit.
__device__ __forceinline__ void gbar(int* bar, int nwg)
{
  __syncthreads();
  if (threadIdx.x == 0) {
    int* cnt = bar;
    int* gen = bar + 1;
    int g = __hip_atomic_load(gen, __ATOMIC_RELAXED, __HIP_MEMORY_SCOPE_AGENT);
    int v = __hip_atomic_fetch_add(cnt, 1, __ATOMIC_ACQ_REL, __HIP_MEMORY_SCOPE_AGENT);
    if (v == nwg - 1) {
      __hip_atomic_store(cnt, 0, __ATOMIC_RELAXED, __HIP_MEMORY_SCOPE_AGENT);
      __hip_atomic_store(gen, g + 1, __ATOMIC_RELEASE, __HIP_MEMORY_SCOPE_AGENT);
    } else {
      while (__hip_atomic_load(gen, __ATOMIC_RELAXED, __HIP_MEMORY_SCOPE_AGENT) == g)
        __builtin_amdgcn_s_sleep(2);
      (void)__hip_atomic_load(gen, __ATOMIC_ACQUIRE, __HIP_MEMORY_SCOPE_AGENT);
    }
  }
  __syncthreads();
}

__global__ __launch_bounds__(256, 1) void seq_kernel(SA a)
{
  const int tid = threadIdx.x, w = tid >> 6, lane = tid & 63;
  const int nwg = gridDim.x, wgid = blockIdx.x;
  const int r = lane & 15, q4 = lane >> 4;
  __shared__ float sm4[4][64][16];
  __shared__ float qs[1024];
  __shared__ float sc[56];

  // ================= encoder: 50 steps =================
  for (int t = 0; t < TSRC; ++t) {
    const int cur = t & 1;
    for (int it = wgid; it < 64; it += nwg) {
      const int dir = it >> 5, j0 = (it & 31) << 4;
      const _Float16* W = (dir ? a.whhR : a.whhF) + (size_t)(w*EH + j0)*EH;
      const _Float16* H = a.h + (size_t)(dir*2 + cur)*NB*EH;
      f32x4 acc[4];
#pragma unroll
      for (int m=0;m<4;++m) acc[m] = 0.f;
      mm16h<EH>(acc, H, EH, W, EH, lane);
#pragma unroll
      for (int m=0;m<4;++m)
#pragma unroll
        for (int e=0;e<4;++e) sm4[w][m*16 + q4*4 + e][r] = acc[m][e];
      __syncthreads();
      const float* xp = (dir ? a.xpR : a.xpF) + (size_t)t*NB*2048;
      float* C = dir ? a.cR : a.cF;
      _Float16* Ho = a.h + (size_t)(dir*2 + (cur^1))*NB*EH;
      const int erow = dir ? (TSRC-1 - t) : t;
      for (int p = tid; p < 1024; p += 256) {
        int b = p >> 4, jj = p & 15, j = j0 + jj;
        float gi = sm4[0][b][jj] + xp[b*2048 + 0*EH + j];
        float gf = sm4[1][b][jj] + xp[b*2048 + 1*EH + j];
        float gg = sm4[2][b][jj] + xp[b*2048 + 2*EH + j];
        float go = sm4[3][b][jj] + xp[b*2048 + 3*EH + j];
        float co = C[b*EH + j];
        float cn = sigm(gf)*co + sigm(gi)*tanhf(gg);
        float hn = sigm(go)*tanhf(cn);
        C[b*EH + j] = cn;
        _Float16 hb = (_Float16)hn;
        Ho[b*EH + j] = hb;
        a.enc_out[((size_t)erow*NB + b)*DH + dir*EH + j] = hb;
        if (t == TSRC-1) {
          a.dh[b*DH + 2*j + dir] = hb;
          a.dc[b*DH + 2*j + dir] = cn;
        }
      }
      __syncthreads();
    }
    gbar(a.bar, nwg);
  }

  // ================= decoder: 49 steps =================
  for (int t = 0; t < TDEC; ++t) {
    // ---- P1: q|gh = h @ [wi ; dWhh]^T (K halves across wave pairs) ----
    for (int it = wgid; it < 160; it += nwg) {
      const int kh = w & 1, col0 = it*32 + (w >> 1)*16;
      const _Float16* W = a.wm1 + (size_t)col0*DH + kh*512;
      f32x4 acc[4];
#pragma unroll
      for (int m=0;m<4;++m) acc[m] = 0.f;
      mm16h<512>(acc, a.dh + kh*512, DH, W, DH, lane);
#pragma unroll
      for (int m=0;m<4;++m)
#pragma unroll
        for (int e=0;e<4;++e) sm4[w][m*16 + q4*4 + e][r] = acc[m][e];
      __syncthreads();
      for (int p = tid; p < 2048; p += 256) {
        int b = p >> 5, cc = p & 31;
        float v = sm4[(cc>>4)*2][b][cc&15] + sm4[(cc>>4)*2 + 1][b][cc&15];
        int C = it*32 + cc;
        if (C < 1024) a.q[b*DH + C] = v;
        else          a.gh[(size_t)b*4096 + C - 1024] = v;
      }
      __syncthreads();
    }
    gbar(a.bar, nwg);

    // ---- P2: attention per batch element (fp16 enc_out, fp32 math) ----
    for (int it = wgid; it < NB; it += nwg) {
      const int b = it;
      for (int i = tid; i < 1024; i += 256) qs[i] = a.q[b*DH + i];
      __syncthreads();
      for (int tt = w; tt < TSRC; tt += 4) {
        const _Float16* er = a.enc_out + ((size_t)tt*NB + b)*DH + lane*16;
        const float* qq = qs + lane*16;
        f16x8 e0 = *(const f16x8*)(er);
        f16x8 e1 = *(const f16x8*)(er + 8);
        float s = 0.f;
#pragma unroll
        for (int ii=0; ii<8; ++ii) s += (float)e0[ii]*qq[ii];
#pragma unroll
        for (int ii=0; ii<8; ++ii) s += (float)e1[ii]*qq[8+ii];
#pragma unroll
        for (int o=32; o; o>>=1) s += __shfl_xor(s, o);
        if (lane == 0) sc[tt] = s;
      }
      __syncthreads();
      float mx = -1e30f;
      for (int tt=0; tt<TSRC; ++tt) mx = fmaxf(mx, sc[tt]);
      __syncthreads();
      if (tid < TSRC) sc[tid] = expf(sc[tid] - mx);
      __syncthreads();
      float s50 = 0.f;
      for (int tt=0; tt<TSRC; ++tt) s50 += sc[tt];
      const float inv = 1.f/s50;
      const int c0 = tid*4;
      float a0=0.f, a1=0.f, a2=0.f, a3=0.f;
      for (int tt=0; tt<TSRC; ++tt) {
        float wt = sc[tt];
        const _Float16* er = a.enc_out + ((size_t)tt*NB + b)*DH + c0;
        a0 += wt*(float)er[0]; a1 += wt*(float)er[1];
        a2 += wt*(float)er[2]; a3 += wt*(float)er[3];
      }
      a.st[b*DH + c0 + 0] = (_Float16)(a0*inv);
      a.st[b*DH + c0 + 1] = (_Float16)(a1*inv);
      a.st[b*DH + c0 + 2] = (_Float16)(a2*inv);
      a.st[b*DH + c0 + 3] = (_Float16)(a3*inv);
      __syncthreads();
    }
    gbar(a.bar, nwg);

    // ---- P3: ct = tanh([st,h] @ wo^T) (st/h halves across wave pairs) ----
    for (int it = wgid; it < 32; it += nwg) {
      const int kh = w & 1, col0 = it*32 + (w >> 1)*16;
      const _Float16* W = a.wo + (size_t)col0*2048 + kh*1024;
      const _Float16* A = kh ? a.dh : a.st;
      f32x4 acc[4];
#pragma unroll
      for (int m=0;m<4;++m) acc[m] = 0.f;
      mm16h<1024>(acc, A, DH, W, 2048, lane);
#pragma unroll
      for (int m=0;m<4;++m)
#pragma unroll
        for (int e=0;e<4;++e) sm4[w][m*16 + q4*4 + e][r] = acc[m][e];
      __syncthreads();
      for (int p = tid; p < 2048; p += 256) {
        int b = p >> 5, cc = p & 31;
        float v = sm4[(cc>>4)*2][b][cc&15] + sm4[(cc>>4)*2 + 1][b][cc&15];
        int C = it*32 + cc;
        a.ct[b*DH + C] = (_Float16)tanhf(v);
      }
      __syncthreads();
    }
    gbar(a.bar, nwg);

    // ---- P4: gates = ct@W + gh + peproj; LSTM update ----
    for (int it = wgid; it < 64; it += nwg) {
      const int j0 = it*16;
      const _Float16* W = a.w3 + (size_t)(w*DH + j0)*1344;
      f32x4 acc[4];
#pragma unroll
      for (int m=0;m<4;++m) acc[m] = 0.f;
      mm16h<1024>(acc, a.ct, DH, W, 1344, lane);
#pragma unroll
      for (int m=0;m<4;++m)
#pragma unroll
        for (int e=0;e<4;++e) sm4[w][m*16 + q4*4 + e][r] = acc[m][e];
      __syncthreads();
      const float* pp = a.pp + (size_t)t*NB*4096;
      for (int p = tid; p < 1024; p += 256) {
        int b = p >> 4, jj = p & 15, j = j0 + jj;
        float gi = sm4[0][b][jj] + a.gh[(size_t)b*4096 + 0*DH + j] + pp[(size_t)b*4096 + 0*DH + j];
        float gf = sm4[1][b][jj] + a.gh[(size_t)b*4096 + 1*DH + j] + pp[(size_t)b*4096 + 1*DH + j];
        float gg = sm4[2][b][jj] + a.gh[(size_t)b*4096 + 2*DH + j] + pp[(size_t)b*4096 + 2*DH + j];
        float go = sm4[3][b][jj] + a.gh[(size_t)b*4096 + 3*DH + j] + pp[(size_t)b*4096 + 3*DH + j];
        float co = a.dc[b*DH + j];
        float cn = sigm(gf)*co + sigm(gi)*tanhf(gg);
        float hn = sigm(go)*tanhf(cn);
        a.dc[b*DH + j] = cn;
        _Float16 hb = (_Float16)hn;
        a.dh[b*DH + j] = hb;
        a.hdec[((size_t)t*NB + b)*DH + j] = hb;
      }
      __syncthreads();
    }
    gbar(a.bar, nwg);
  }
}

// ---------------- in-place log-softmax over vocab rows ----------------
__global__ __launch_bounds__(256) void lsm(float* __restrict__ out)
{
  const int row = NB + blockIdx.x;  // rows 64..3199
  float* p = out + (size_t)row*GV;
  const int tid = threadIdx.x;
  __shared__ float red[4], red2[4];
  float mx = -1e30f;
  for (int i = tid; i < GV; i += 256) mx = fmaxf(mx, p[i]);
  for (int off=32; off; off>>=1) mx = fmaxf(mx, __shfl_down(mx, off));
  if ((tid & 63) == 0) red[tid>>6] = mx;
  __syncthreads();
  mx = fmaxf(fmaxf(red[0],red[1]), fmaxf(red[2],red[3]));
  float sm = 0.f;
  for (int i = tid; i < GV; i += 256) sm += expf(p[i] - mx);
  for (int off=32; off; off>>=1) sm += __shfl_down(sm, off);
  if ((tid & 63) == 0) red2[tid>>6] = sm;
  __syncthreads();
  sm = red2[0]+red2[1]+red2[2]+red2[3];
  float lse = mx + logf(sm);
  for (int i = tid; i < GV; i += 256) p[i] -= lse;
}

// ---------------- host ----------------
extern "C" void kernel_launch(void* const* d_in, const int* in_sizes, int n_in,
                              void* d_out, int out_size, void* d_ws, size_t ws_size,
                              hipStream_t stream)
{
  const int*   src  = (const int*)d_in[0];
  const int*   trg  = (const int*)d_in[1];
  const float* WihF = (const float*)d_in[2];
  const float* WhhF = (const float*)d_in[3];
  const float* bihF = (const float*)d_in[4];
  const float* bhhF = (const float*)d_in[5];
  const float* WihR = (const float*)d_in[6];
  const float* WhhR = (const float*)d_in[7];
  const float* bihR = (const float*)d_in[8];
  const float* bhhR = (const float*)d_in[9];
  const float* dWih = (const float*)d_in[10];
  const float* dWhh = (const float*)d_in[11];
  const float* dbih = (const float*)d_in[12];
  const float* dbhh = (const float*)d_in[13];
  const float* eemb = (const float*)d_in[14];
  const float* demb = (const float*)d_in[15];
  const float* wi   = (const float*)d_in[16];
  const float* wo   = (const float*)d_in[17];
  const float* genw = (const float*)d_in[18];
  const float* genb = (const float*)d_in[19];
  float* out = (float*)d_out;

  char* ws = (char*)d_ws;
  size_t off = 0;
  auto alloc = [&](size_t bytes)->char* {
    char* p = ws + off; off = (off + bytes + 255) & ~(size_t)255; return p;
  };
  _Float16* x_h    = (_Float16*)alloc((size_t)TSRC*NB*EMBP*2);
  _Float16* xrev_h = (_Float16*)alloc((size_t)TSRC*NB*EMBP*2);
  _Float16* pe_h   = (_Float16*)alloc((size_t)TDEC*NB*EMBP*2);
  _Float16* wihF_h = (_Float16*)alloc((size_t)2048*EMBP*2);
  _Float16* wihR_h = (_Float16*)alloc((size_t)2048*EMBP*2);
  _Float16* whhF_h = (_Float16*)alloc((size_t)2048*EH*2);
  _Float16* whhR_h = (_Float16*)alloc((size_t)2048*EH*2);
  _Float16* wm1_h  = (_Float16*)alloc((size_t)5120*DH*2);
  _Float16* wo_h   = (_Float16*)alloc((size_t)DH*2048*2);
  _Float16* wih3_h = (_Float16*)alloc((size_t)4096*1344*2);
  _Float16* genw_h = (_Float16*)alloc((size_t)GVP*DH*2);
  float* b4f   = (float*)alloc(2048*4);
  float* b4r   = (float*)alloc(2048*4);
  float* db4   = (float*)alloc(4096*4);
  float* xp_f  = (float*)alloc((size_t)TSRC*NB*2048*4);
  float* xp_r  = (float*)alloc((size_t)TSRC*NB*2048*4);
  float* peproj = (float*)alloc((size_t)TDEC*NB*4096*4);
  _Float16* enc_out = (_Float16*)alloc((size_t)TSRC*NB*DH*2);
  _Float16* hbuf = (_Float16*)alloc((size_t)4*NB*EH*2);
  float* cf = (float*)alloc((size_t)NB*EH*4);
  float* cr = (float*)alloc((size_t)NB*EH*4);
  _Float16* dh = (_Float16*)alloc((size_t)NB*DH*2);
  float* dc = (float*)alloc((size_t)NB*DH*4);
  float* qb = (float*)alloc((size_t)NB*DH*4);
  float* gh = (float*)alloc((size_t)NB*4096*4);
  _Float16* st = (_Float16*)alloc((size_t)NB*DH*2);
  _Float16* ct = (_Float16*)alloc((size_t)NB*DH*2);
  _Float16* hdec = (_Float16*)alloc((size_t)3200*DH*2);
  int* bar = (int*)alloc(256);
  (void)in_sizes; (void)n_in; (void)out_size; (void)ws_size;

  // --- init / zero state (every call: graph replays don't re-poison) ---
  hipMemsetAsync(hbuf, 0, (size_t)4*NB*EH*2, stream);
  hipMemsetAsync(cf, 0, (size_t)NB*EH*4, stream);
  hipMemsetAsync(cr, 0, (size_t)NB*EH*4, stream);
  hipMemsetAsync(hdec + (size_t)3136*DH, 0, (size_t)64*DH*2, stream);
  hipMemsetAsync(genw_h + (size_t)GV*DH, 0, (size_t)(GVP-GV)*DH*2, stream);
  hipMemsetAsync(out, 0, (size_t)NB*GV*4, stream);   // timestep 0 = zeros
  hipMemsetAsync(bar, 0, 256, stream);

  auto cgrid = [](size_t n){ return dim3((unsigned)((n + 255)/256)); };

  // --- weight conversion (fp16) ---
  cvt16<<<cgrid((size_t)2048*EMBP),256,0,stream>>>(WihF, wihF_h, 2048, EMBD, EMBP);
  cvt16<<<cgrid((size_t)2048*EMBP),256,0,stream>>>(WihR, wihR_h, 2048, EMBD, EMBP);
  cvt16<<<cgrid((size_t)2048*EH),256,0,stream>>>(WhhF, whhF_h, 2048, EH, EH);
  cvt16<<<cgrid((size_t)2048*EH),256,0,stream>>>(WhhR, whhR_h, 2048, EH, EH);
  cvt16<<<cgrid((size_t)1024*DH),256,0,stream>>>(wi, wm1_h, 1024, DH, DH);
  cvt16<<<cgrid((size_t)4096*DH),256,0,stream>>>(dWhh, wm1_h + (size_t)1024*DH, 4096, DH, DH);
  cvt16<<<cgrid((size_t)DH*2048),256,0,stream>>>(wo, wo_h, DH, 2048, 2048);
  cvt16<<<cgrid((size_t)4096*1344),256,0,stream>>>(dWih, wih3_h, 4096, 1324, 1344);
  cvt16<<<cgrid((size_t)GV*DH),256,0,stream>>>(genw, genw_h, GV, DH, DH);
  addb<<<cgrid(2048),256,0,stream>>>(bihF, bhhF, b4f, 2048);
  addb<<<cgrid(2048),256,0,stream>>>(bihR, bhhR, b4r, 2048);
  addb<<<cgrid(4096),256,0,stream>>>(dbih, dbhh, db4, 4096);
  k_embed<<<cgrid((size_t)(TSRC+TDEC)*NB*EMBP),256,0,stream>>>(src, trg, eemb, demb, x_h, xrev_h, pe_h);

  // --- encoder input projections (bias folded in) + pe projection for decoder ---
  gemm128<<<dim3(16,25),256,0,stream>>>(x_h,    EMBP, wihF_h, EMBP, b4f, xp_f, 2048, EMBP, 3200, 2048, 0);
  gemm128<<<dim3(16,25),256,0,stream>>>(xrev_h, EMBP, wihR_h, EMBP, b4r, xp_r, 2048, EMBP, 3200, 2048, 0);
  gemm128<<<dim3(32,25),256,0,stream>>>(pe_h, EMBP, wih3_h + 1024, 1344, db4, peproj, 4096, EMBP, 3136, 4096, 0);

  // --- persistent sequential kernel: encoder + decoder ---
  SA sa;
  sa.whhF = whhF_h; sa.whhR = whhR_h;
  sa.wm1 = wm1_h;
  sa.wo = wo_h;
  sa.w3 = wih3_h;
  sa.xpF = xp_f; sa.xpR = xp_r;
  sa.pp = peproj;
  sa.h = hbuf;
  sa.cF = cf; sa.cR = cr;
  sa.enc_out = enc_out;
  sa.dh = dh; sa.dc = dc;
  sa.q = qb; sa.gh = gh;
  sa.st = st; sa.ct = ct;
  sa.hdec = hdec;
  sa.bar = bar;
  seq_kernel<<<dim3(GRID), 256, 0, stream>>>(sa);

  // --- generator: logits into d_out rows 64.. (t+1 shift), then log-softmax ---
  gemm128<<<dim3(GVP/128,25),256,0,stream>>>(hdec, DH, genw_h, DH, genb, out, GV, DH, 3136, GV, NB);
  lsm<<<3136,256,0,stream>>>(out);
}

// Round 6
// 6322.741 us; speedup vs baseline: 6.4201x; 1.1398x over previous
//
#include <hip/hip_runtime.h>
#include <cstdint>
#include <cmath>

// ---------------- dims ----------------
#define NB    64      // batch
#define EMBD  300
#define EMBP  320     // padded K for embedding-side GEMMs
#define EH    512     // encoder hidden
#define DH    1024    // decoder hidden
#define GV    23262   // target vocab
#define GVP   23296   // padded to 182*128
#define TSRC  50
#define TDEC  49      // decoder steps
#define GRIDN 248     // persistent WGs (<=256 CUs, 1 WG/CU due to LDS)
#define NUNITS 416    // 64 enc + 160 P1 + 64 P3 + 128 P4 (64 KB weight units)
#define LDS_SCR 131072            // scratch region offset (after 2x64KB weight slots)
#define LDS_TOT (131072 + 16384)  // 144 KB dynamic LDS per WG

typedef __attribute__((ext_vector_type(8))) _Float16 f16x8;
typedef __attribute__((ext_vector_type(4))) float f32x4;

__device__ __forceinline__ float sigm(float x){ return 1.f/(1.f+expf(-x)); }

// ---- stage a [nrows][ncols] fp16 tile (row stride srcld elems) into LDS with
// XOR-16B swizzle: byte = row*ncols*2 + ((c*16) ^ ((row&7)<<4)). 16 rows at
// stride>=1024B would otherwise be a 16-way bank conflict on ds_read_b128 (G4).
__device__ __forceinline__ void stageW(char* dst, const _Float16* __restrict__ src,
                                       int srcld, int nrows, int ncols, int tid)
{
  const int nch = ncols >> 3;
  for (int i = tid; i < nrows*nch; i += 256) {
    int row = i / nch, c = i - row*nch;
    *(f16x8*)(dst + row*ncols*2 + ((c*16) ^ ((row&7)<<4))) =
        *(const f16x8*)(src + (size_t)row*srcld + c*8);
  }
}

// 64x16 MFMA tile, K=512: acc += A[64][512](global fp16) @ B[16][512](LDS)^T.
// B read with the staging swizzle; koffB = byte offset of this wave's K-range
// (multiple of 1024 -> additive outside the XOR). 4-slice A staging groups keep
// ~16 global loads in flight per wave.
__device__ __forceinline__ void mm16_lds512(f32x4 (&acc)[4],
    const _Float16* __restrict__ A, int lda,
    const char* ldsB, int rowbytes, int koffB, int lane)
{
  const int r = lane & 15, q = lane >> 4;
  const _Float16* a0 = A + r*lda + q*8;
  const char* b0 = ldsB + r*rowbytes + koffB;
  const int sw = (r & 7) << 4;
#pragma unroll
  for (int g = 0; g < 4; ++g) {
    f16x8 av[4][4], bv[4];
#pragma unroll
    for (int s = 0; s < 4; ++s) {
      int sl = g*4 + s;
      bv[s] = *(const f16x8*)(b0 + ((sl*64 + q*16) ^ sw));
#pragma unroll
      for (int m = 0; m < 4; ++m)
        av[s][m] = *(const f16x8*)(a0 + m*16*lda + sl*32);
    }
#pragma unroll
    for (int s = 0; s < 4; ++s)
#pragma unroll
      for (int m = 0; m < 4; ++m)
        acc[m] = __builtin_amdgcn_mfma_f32_16x16x32_f16(av[s][m], bv[s], acc[m], 0, 0, 0);
  }
}

// ---------------- prep kernels ----------------
__global__ void cvt16s(const float* __restrict__ src, _Float16* __restrict__ dst,
                       int rows, int sld, int scols, int dcols)
{
  int idx = blockIdx.x*256 + threadIdx.x;
  if (idx >= rows*dcols) return;
  int c = idx % dcols, rr = idx / dcols;
  dst[idx] = (c < scols) ? (_Float16)src[(size_t)rr*sld + c] : (_Float16)0.f;
}

__global__ void addb(const float* __restrict__ a, const float* __restrict__ b,
                     float* __restrict__ o, int n)
{
  int i = blockIdx.x*256 + threadIdx.x;
  if (i < n) o[i] = a[i] + b[i];
}

__global__ void k_embed(const int* __restrict__ src, const int* __restrict__ trg,
                        const float* __restrict__ eemb, const float* __restrict__ demb,
                        _Float16* __restrict__ x_h, _Float16* __restrict__ xrev_h,
                        _Float16* __restrict__ pe_h)
{
  int idx = blockIdx.x*256 + threadIdx.x;
  const int tot1 = TSRC*NB*EMBP;
  const int tot2 = TDEC*NB*EMBP;
  if (idx < tot1) {
    int e = idx % EMBP, rb = idx / EMBP;
    int t = rb >> 6, b = rb & 63;
    float v = 0.f;
    if (e < EMBD) v = eemb[(size_t)src[rb]*EMBD + e];
    _Float16 hv = (_Float16)v;
    x_h[idx] = hv;
    xrev_h[(size_t)((TSRC-1-t)*NB + b)*EMBP + e] = hv;
  } else if (idx < tot1 + tot2) {
    int k = idx - tot1;
    int e = k % EMBP, rb = k / EMBP;
    float v = 0.f;
    if (e < EMBD) v = demb[(size_t)trg[rb]*EMBD + e];
    pe_h[k] = (_Float16)v;
  }
}

// ---------------- big tiled GEMM (throughput path: proj + peproj + generator), fp16 ----------------
__global__ __launch_bounds__(256) void gemm128(
    const _Float16* __restrict__ A, int lda,
    const _Float16* __restrict__ W, int ldw,
    const float* __restrict__ bias,
    float* __restrict__ out, int ldo,
    int K, int mvalid, int nvalid, int rowoff)
{
  __shared__ _Float16 As[128*64];
  __shared__ _Float16 Bs[128*64];
  const int tid = threadIdx.x;
  const int m0 = blockIdx.y*128, n0 = blockIdx.x*128;
  const int w = tid >> 6, lane = tid & 63, r = lane & 15, q = lane >> 4;
  const int mw = (w >> 1)*64, nw = (w & 1)*64;
  f32x4 acc[4][4];
#pragma unroll
  for (int mi=0; mi<4; ++mi)
#pragma unroll
    for (int ni=0; ni<4; ++ni) acc[mi][ni] = 0.f;

  for (int kt = 0; kt < K; kt += 64) {
    f16x8 ra[4], rb[4];
#pragma unroll
    for (int j = 0; j < 4; ++j) {
      int c = j*256 + tid, row = c >> 3, cc = c & 7;
      ra[j] = *(const f16x8*)(A + (size_t)(m0+row)*lda + kt + cc*8);
      rb[j] = *(const f16x8*)(W + (size_t)(n0+row)*ldw + kt + cc*8);
    }
    __syncthreads();
#pragma unroll
    for (int j = 0; j < 4; ++j) {
      int c = j*256 + tid, row = c >> 3, cc = c & 7;
      int sw = cc ^ (row & 7);
      *(f16x8*)((char*)As + row*128 + (sw<<4)) = ra[j];
      *(f16x8*)((char*)Bs + row*128 + (sw<<4)) = rb[j];
    }
    __syncthreads();
#pragma unroll
    for (int kk = 0; kk < 64; kk += 32) {
      int ch = (kk >> 3) + q;
      f16x8 av[4], bv[4];
#pragma unroll
      for (int mi=0; mi<4; ++mi) {
        int row = mw + mi*16 + r;
        av[mi] = *(const f16x8*)((char*)As + row*128 + ((ch ^ (row&7))<<4));
      }
#pragma unroll
      for (int ni=0; ni<4; ++ni) {
        int row = nw + ni*16 + r;
        bv[ni] = *(const f16x8*)((char*)Bs + row*128 + ((ch ^ (row&7))<<4));
      }
#pragma unroll
      for (int mi=0; mi<4; ++mi)
#pragma unroll
        for (int ni=0; ni<4; ++ni)
          acc[mi][ni] = __builtin_amdgcn_mfma_f32_16x16x32_f16(av[mi], bv[ni], acc[mi][ni], 0,0,0);
    }
  }
#pragma unroll
  for (int mi=0; mi<4; ++mi)
#pragma unroll
    for (int ni=0; ni<4; ++ni)
#pragma unroll
      for (int e=0; e<4; ++e) {
        int mrow = m0 + mw + mi*16 + q*4 + e;
        int col  = n0 + nw + ni*16 + r;
        if (mrow < mvalid && col < nvalid)
          out[(size_t)(mrow + rowoff)*ldo + col] = acc[mi][ni][e] + bias[col];
      }
}

// ---------------- persistent weight-stationary sequential kernel ----------------
struct SA {
  const _Float16 *whhF, *whhR;   // [2048][512]
  const _Float16 *wm1;           // [5120][1024]  ([wi ; dWhh])
  const _Float16 *wo;            // [1024][2048]
  const _Float16 *w3c;           // [4096][1024]  (dWih ct-part, contiguous)
  const float *xpF, *xpR;        // [50*64][2048] (bias included)
  const float *pp;               // [49*64][4096] pe@dWih_pe + biases
  _Float16 *h;                   // [2 dir][2 buf][64][512]
  float *cF, *cR;                // [64][512]
  _Float16 *enc_out;             // [50][64][1024]
  _Float16 *dh;                  // [64][1024]
  float *dc;                     // [64][1024]
  float *q;                      // [64][1024]
  float *gh;                     // [64][4096]
  _Float16 *st, *ct;             // [64][1024]
  float *gates4;                 // [64][4096]
  _Float16 *hdec;                // [3200][1024]
  int *bar;                      // [cnt, gen]
};

// Subset grid barrier with local epoch: only `part` WGs arrive (cost ~ target),
// everyone polls the generation counter. Release on bump, acquire on exit.
__device__ __forceinline__ void gbar(int* bar, int& myg, bool part, int target)
{
  __syncthreads();
  ++myg;
  if (threadIdx.x == 0) {
    int* cnt = bar;
    int* gen = bar + 1;
    if (part) {
      int v = __hip_atomic_fetch_add(cnt, 1, __ATOMIC_ACQ_REL, __HIP_MEMORY_SCOPE_AGENT);
      if (v == target - 1) {
        __hip_atomic_store(cnt, 0, __ATOMIC_RELAXED, __HIP_MEMORY_SCOPE_AGENT);
        __hip_atomic_store(gen, myg, __ATOMIC_RELEASE, __HIP_MEMORY_SCOPE_AGENT);
      }
    }
    while (__hip_atomic_load(gen, __ATOMIC_RELAXED, __HIP_MEMORY_SCOPE_AGENT) < myg)
      __builtin_amdgcn_s_sleep(2);
    (void)__hip_atomic_load(gen, __ATOMIC_ACQUIRE, __HIP_MEMORY_SCOPE_AGENT);
  }
  __syncthreads();
}

__global__ __launch_bounds__(256, 1) void seq_kernel(SA a)
{
  extern __shared__ char lds[];
  const int tid = threadIdx.x, w = tid >> 6, lane = tid & 63;
  const int wgid = blockIdx.x;
  const int r = lane & 15, q4 = lane >> 4;
  float (*sm4)[64][16] = (float(*)[64][16])(lds + LDS_SCR);
  float* qs = (float*)(lds + LDS_SCR);          // P2 only (aliases sm4, phase-separated)
  float* sc = (float*)(lds + LDS_SCR + 4096);

  // ---- stage this WG's weight units into LDS (once) ----
  // unit u -> WG u % GRIDN, slot = u / GRIDN. layout:
  //   u in [0,64)    : ENC  (dir=u>>5, jblk=u&31)   4 x [16][512]
  //   u in [64,224)  : P1   col-block 32 of [5120][1024]
  //   u in [224,288) : P3   col-block 16 of [1024][2048]
  //   u in [288,416) : P4   col-block 32 of [4096][1024]
  for (int s = 0; s < 2; ++s) {
    int u = wgid + s*GRIDN;
    if (u >= NUNITS) break;
    char* dst = lds + s*65536;
    if (u < 64) {
      int dir = u >> 5, j0 = (u & 31) << 4;
      const _Float16* whh = dir ? a.whhR : a.whhF;
      for (int g = 0; g < 4; ++g)
        stageW(dst + g*16384, whh + (size_t)(g*EH + j0)*EH, EH, 16, 512, tid);
    } else if (u < 224) {
      stageW(dst, a.wm1 + (size_t)(u-64)*32*DH, DH, 32, 1024, tid);
    } else if (u < 288) {
      stageW(dst, a.wo + (size_t)(u-224)*16*2048, 2048, 16, 2048, tid);
    } else {
      stageW(dst, a.w3c + (size_t)(u-288)*32*DH, DH, 32, 1024, tid);
    }
  }
  __syncthreads();   // own LDS only -> no grid barrier needed

  int myg = 0;

  // ================= encoder: 50 steps (WGs 0-63) =================
  for (int t = 0; t < TSRC; ++t) {
    const bool part = (wgid < 64);
    if (part) {
      const int dir = wgid >> 5, j0 = (wgid & 31) << 4;
      const int cur = t & 1;
      const _Float16* H = a.h + (size_t)(dir*2 + cur)*NB*EH;
      f32x4 acc[4];
#pragma unroll
      for (int m=0;m<4;++m) acc[m] = 0.f;
      // wave w = gate w: B tile [16][512] at lds + w*16KB
      mm16_lds512(acc, H, EH, lds + w*16384, 1024, 0, lane);
#pragma unroll
      for (int m=0;m<4;++m)
#pragma unroll
        for (int e=0;e<4;++e) sm4[w][m*16 + q4*4 + e][r] = acc[m][e];
      __syncthreads();
      const float* xp = (dir ? a.xpR : a.xpF) + (size_t)t*NB*2048;
      float* C = dir ? a.cR : a.cF;
      _Float16* Ho = a.h + (size_t)(dir*2 + (cur^1))*NB*EH;
      const int erow = dir ? (TSRC-1 - t) : t;
      for (int p = tid; p < 1024; p += 256) {
        int b = p >> 4, jj = p & 15, j = j0 + jj;
        float gi = sm4[0][b][jj] + xp[b*2048 + 0*EH + j];
        float gf = sm4[1][b][jj] + xp[b*2048 + 1*EH + j];
        float gg = sm4[2][b][jj] + xp[b*2048 + 2*EH + j];
        float go = sm4[3][b][jj] + xp[b*2048 + 3*EH + j];
        float co = C[b*EH + j];
        float cn = sigm(gf)*co + sigm(gi)*tanhf(gg);
        float hn = sigm(go)*tanhf(cn);
        C[b*EH + j] = cn;
        _Float16 hb = (_Float16)hn;
        Ho[b*EH + j] = hb;
        a.enc_out[((size_t)erow*NB + b)*DH + dir*EH + j] = hb;
        if (t == TSRC-1) {
          a.dh[b*DH + 2*j + dir] = hb;
          a.dc[b*DH + 2*j + dir] = cn;
        }
      }
    }
    gbar(a.bar, myg, part, 64);
  }

  // ================= decoder: 49 steps =================
  for (int t = 0; t < TDEC; ++t) {
    // ---- P1: q|gh = dh @ [wi ; dWhh]^T  (WGs 64-223, unit=32 cols, waves: 16-col x K-half) ----
    {
      const bool part = (wgid >= 64 && wgid < 224);
      if (part) {
        const int col0 = (wgid - 64)*32;
        const int cs = w >> 1, kh = w & 1;
        f32x4 acc[4];
#pragma unroll
        for (int m=0;m<4;++m) acc[m] = 0.f;
        mm16_lds512(acc, a.dh + kh*512, DH, lds + cs*16*2048, 2048, kh*1024, lane);
#pragma unroll
        for (int m=0;m<4;++m)
#pragma unroll
          for (int e=0;e<4;++e) sm4[w][m*16 + q4*4 + e][r] = acc[m][e];
        __syncthreads();
        for (int p = tid; p < 2048; p += 256) {
          int b = p >> 5, cc = p & 31;
          float v = sm4[(cc>>4)*2][b][cc&15] + sm4[(cc>>4)*2 + 1][b][cc&15];
          int C = col0 + cc;
          if (C < 1024) a.q[b*DH + C] = v;
          else          a.gh[(size_t)b*4096 + C - 1024] = v;
        }
      }
      gbar(a.bar, myg, part, 160);
    }

    // ---- P2: attention (WGs 0-63, one batch element each) ----
    {
      const bool part = (wgid < 64);
      if (part) {
        const int b = wgid;
        for (int i = tid; i < 1024; i += 256) qs[i] = a.q[b*DH + i];
        __syncthreads();
        for (int tt = w; tt < TSRC; tt += 4) {
          const _Float16* er = a.enc_out + ((size_t)tt*NB + b)*DH + lane*16;
          const float* qq = qs + lane*16;
          f16x8 e0 = *(const f16x8*)(er);
          f16x8 e1 = *(const f16x8*)(er + 8);
          float s = 0.f;
#pragma unroll
          for (int ii=0; ii<8; ++ii) s += (float)e0[ii]*qq[ii];
#pragma unroll
          for (int ii=0; ii<8; ++ii) s += (float)e1[ii]*qq[8+ii];
#pragma unroll
          for (int o=32; o; o>>=1) s += __shfl_xor(s, o);
          if (lane == 0) sc[tt] = s;
        }
        __syncthreads();
        float mx = -1e30f;
        for (int tt=0; tt<TSRC; ++tt) mx = fmaxf(mx, sc[tt]);
        __syncthreads();
        if (tid < TSRC) sc[tid] = expf(sc[tid] - mx);
        __syncthreads();
        float s50 = 0.f;
        for (int tt=0; tt<TSRC; ++tt) s50 += sc[tt];
        const float inv = 1.f/s50;
        const int c0 = tid*4;
        float a0=0.f, a1=0.f, a2=0.f, a3=0.f;
        for (int tt=0; tt<TSRC; ++tt) {
          float wt = sc[tt];
          const _Float16* er = a.enc_out + ((size_t)tt*NB + b)*DH + c0;
          a0 += wt*(float)er[0]; a1 += wt*(float)er[1];
          a2 += wt*(float)er[2]; a3 += wt*(float)er[3];
        }
        a.st[b*DH + c0 + 0] = (_Float16)(a0*inv);
        a.st[b*DH + c0 + 1] = (_Float16)(a1*inv);
        a.st[b*DH + c0 + 2] = (_Float16)(a2*inv);
        a.st[b*DH + c0 + 3] = (_Float16)(a3*inv);
      }
      gbar(a.bar, myg, part, 64);
    }

    // ---- P3: ct = tanh([st,dh] @ wo^T)  (WGs 224-247 slot0 + 0-39 slot1; unit=16 cols, waves=K quarters) ----
    {
      const bool p0 = (wgid >= 224), p1 = (wgid < 40);
      const bool part = p0 || p1;
      if (part) {
        const int idx  = p0 ? (wgid - 224) : (wgid + 24);
        const char* ldsB = lds + (p0 ? 0 : 65536);
        const int col0 = idx*16;
        const _Float16* A = (w < 2 ? a.st : a.dh) + (w & 1)*512;
        f32x4 acc[4];
#pragma unroll
        for (int m=0;m<4;++m) acc[m] = 0.f;
        mm16_lds512(acc, A, DH, ldsB, 4096, w*1024, lane);
#pragma unroll
        for (int m=0;m<4;++m)
#pragma unroll
          for (int e=0;e<4;++e) sm4[w][m*16 + q4*4 + e][r] = acc[m][e];
        __syncthreads();
        for (int p = tid; p < 1024; p += 256) {
          int b = p >> 4, jj = p & 15;
          float v = sm4[0][b][jj] + sm4[1][b][jj] + sm4[2][b][jj] + sm4[3][b][jj];
          a.ct[b*DH + col0 + jj] = (_Float16)tanhf(v);
        }
      }
      gbar(a.bar, myg, part, 64);
    }

    // ---- P4a: gates4 = ct @ w3c^T  (WGs 40-167 slot1, unit=32 cols of [4096]) ----
    {
      const bool part = (wgid >= 40 && wgid < 168);
      if (part) {
        const int col0 = (wgid - 40)*32;
        const int cs = w >> 1, kh = w & 1;
        f32x4 acc[4];
#pragma unroll
        for (int m=0;m<4;++m) acc[m] = 0.f;
        mm16_lds512(acc, a.ct + kh*512, DH, lds + 65536 + cs*16*2048, 2048, kh*1024, lane);
#pragma unroll
        for (int m=0;m<4;++m)
#pragma unroll
          for (int e=0;e<4;++e) sm4[w][m*16 + q4*4 + e][r] = acc[m][e];
        __syncthreads();
        for (int p = tid; p < 2048; p += 256) {
          int b = p >> 5, cc = p & 31;
          float v = sm4[(cc>>4)*2][b][cc&15] + sm4[(cc>>4)*2 + 1][b][cc&15];
          a.gates4[(size_t)b*4096 + col0 + cc] = v;
        }
      }
      gbar(a.bar, myg, part, 128);
    }

    // ---- P4b: LSTM update (WGs 64-127, 1024 elems each) ----
    {
      const bool part = (wgid >= 64 && wgid < 128);
      if (part) {
        const int base = (wgid - 64)*1024;
        const float* pp = a.pp + (size_t)t*NB*4096;
        for (int p = tid; p < 1024; p += 256) {
          int idx = base + p;
          int b = idx >> 10, j = idx & 1023;
          float gi = a.gates4[(size_t)b*4096 + 0*DH + j] + a.gh[(size_t)b*4096 + 0*DH + j] + pp[(size_t)b*4096 + 0*DH + j];
          float gf = a.gates4[(size_t)b*4096 + 1*DH + j] + a.gh[(size_t)b*4096 + 1*DH + j] + pp[(size_t)b*4096 + 1*DH + j];
          float gg = a.gates4[(size_t)b*4096 + 2*DH + j] + a.gh[(size_t)b*4096 + 2*DH + j] + pp[(size_t)b*4096 + 2*DH + j];
          float go = a.gates4[(size_t)b*4096 + 3*DH + j] + a.gh[(size_t)b*4096 + 3*DH + j] + pp[(size_t)b*4096 + 3*DH + j];
          float co = a.dc[b*DH + j];
          float cn = sigm(gf)*co + sigm(gi)*tanhf(gg);
          float hn = sigm(go)*tanhf(cn);
          a.dc[b*DH + j] = cn;
          _Float16 hb = (_Float16)hn;
          a.dh[b*DH + j] = hb;
          a.hdec[((size_t)t*NB + b)*DH + j] = hb;
        }
      }
      gbar(a.bar, myg, part, 64);
    }
  }
}

// ---------------- in-place log-softmax over vocab rows ----------------
__global__ __launch_bounds__(256) void lsm(float* __restrict__ out)
{
  const int row = NB + blockIdx.x;  // rows 64..3199
  float* p = out + (size_t)row*GV;
  const int tid = threadIdx.x;
  __shared__ float red[4], red2[4];
  float mx = -1e30f;
  for (int i = tid; i < GV; i += 256) mx = fmaxf(mx, p[i]);
  for (int off=32; off; off>>=1) mx = fmaxf(mx, __shfl_down(mx, off));
  if ((tid & 63) == 0) red[tid>>6] = mx;
  __syncthreads();
  mx = fmaxf(fmaxf(red[0],red[1]), fmaxf(red[2],red[3]));
  float sm = 0.f;
  for (int i = tid; i < GV; i += 256) sm += expf(p[i] - mx);
  for (int off=32; off; off>>=1) sm += __shfl_down(sm, off);
  if ((tid & 63) == 0) red2[tid>>6] = sm;
  __syncthreads();
  sm = red2[0]+red2[1]+red2[2]+red2[3];
  float lse = mx + logf(sm);
  for (int i = tid; i < GV; i += 256) p[i] -= lse;
}

// ---------------- host ----------------
extern "C" void kernel_launch(void* const* d_in, const int* in_sizes, int n_in,
                              void* d_out, int out_size, void* d_ws, size_t ws_size,
                              hipStream_t stream)
{
  const int*   src  = (const int*)d_in[0];
  const int*   trg  = (const int*)d_in[1];
  const float* WihF = (const float*)d_in[2];
  const float* WhhF = (const float*)d_in[3];
  const float* bihF = (const float*)d_in[4];
  const float* bhhF = (const float*)d_in[5];
  const float* WihR = (const float*)d_in[6];
  const float* WhhR = (const float*)d_in[7];
  const float* bihR = (const float*)d_in[8];
  const float* bhhR = (const float*)d_in[9];
  const float* dWih = (const float*)d_in[10];
  const float* dWhh = (const float*)d_in[11];
  const float* dbih = (const float*)d_in[12];
  const float* dbhh = (const float*)d_in[13];
  const float* eemb = (const float*)d_in[14];
  const float* demb = (const float*)d_in[15];
  const float* wi   = (const float*)d_in[16];
  const float* wo   = (const float*)d_in[17];
  const float* genw = (const float*)d_in[18];
  const float* genb = (const float*)d_in[19];
  float* out = (float*)d_out;

  char* ws = (char*)d_ws;
  size_t off = 0;
  auto alloc = [&](size_t bytes)->char* {
    char* p = ws + off; off = (off + bytes + 255) & ~(size_t)255; return p;
  };
  _Float16* x_h    = (_Float16*)alloc((size_t)TSRC*NB*EMBP*2);
  _Float16* xrev_h = (_Float16*)alloc((size_t)TSRC*NB*EMBP*2);
  _Float16* pe_h   = (_Float16*)alloc((size_t)TDEC*NB*EMBP*2);
  _Float16* wihF_h = (_Float16*)alloc((size_t)2048*EMBP*2);
  _Float16* wihR_h = (_Float16*)alloc((size_t)2048*EMBP*2);
  _Float16* whhF_h = (_Float16*)alloc((size_t)2048*EH*2);
  _Float16* whhR_h = (_Float16*)alloc((size_t)2048*EH*2);
  _Float16* wm1_h  = (_Float16*)alloc((size_t)5120*DH*2);
  _Float16* wo_h   = (_Float16*)alloc((size_t)DH*2048*2);
  _Float16* w3c    = (_Float16*)alloc((size_t)4096*DH*2);
  _Float16* w3pe   = (_Float16*)alloc((size_t)4096*EMBP*2);
  _Float16* genw_h = (_Float16*)alloc((size_t)GVP*DH*2);
  float* b4f   = (float*)alloc(2048*4);
  float* b4r   = (float*)alloc(2048*4);
  float* db4   = (float*)alloc(4096*4);
  float* xp_f  = (float*)alloc((size_t)TSRC*NB*2048*4);
  float* xp_r  = (float*)alloc((size_t)TSRC*NB*2048*4);
  float* peproj = (float*)alloc((size_t)TDEC*NB*4096*4);
  _Float16* enc_out = (_Float16*)alloc((size_t)TSRC*NB*DH*2);
  _Float16* hbuf = (_Float16*)alloc((size_t)4*NB*EH*2);
  float* cf = (float*)alloc((size_t)NB*EH*4);
  float* cr = (float*)alloc((size_t)NB*EH*4);
  _Float16* dh = (_Float16*)alloc((size_t)NB*DH*2);
  float* dc = (float*)alloc((size_t)NB*DH*4);
  float* qb = (float*)alloc((size_t)NB*DH*4);
  float* gh = (float*)alloc((size_t)NB*4096*4);
  _Float16* st = (_Float16*)alloc((size_t)NB*DH*2);
  _Float16* ct = (_Float16*)alloc((size_t)NB*DH*2);
  float* gates4 = (float*)alloc((size_t)NB*4096*4);
  _Float16* hdec = (_Float16*)alloc((size_t)3200*DH*2);
  int* bar = (int*)alloc(256);
  (void)in_sizes; (void)n_in; (void)out_size; (void)ws_size;

  // --- init / zero state (every call: graph replays don't re-poison) ---
  hipMemsetAsync(hbuf, 0, (size_t)4*NB*EH*2, stream);
  hipMemsetAsync(cf, 0, (size_t)NB*EH*4, stream);
  hipMemsetAsync(cr, 0, (size_t)NB*EH*4, stream);
  hipMemsetAsync(hdec + (size_t)3136*DH, 0, (size_t)64*DH*2, stream);
  hipMemsetAsync(genw_h + (size_t)GV*DH, 0, (size_t)(GVP-GV)*DH*2, stream);
  hipMemsetAsync(out, 0, (size_t)NB*GV*4, stream);   // timestep 0 = zeros
  hipMemsetAsync(bar, 0, 256, stream);

  auto cgrid = [](size_t n){ return dim3((unsigned)((n + 255)/256)); };

  // --- weight conversion (fp16) ---
  cvt16s<<<cgrid((size_t)2048*EMBP),256,0,stream>>>(WihF, wihF_h, 2048, EMBD, EMBD, EMBP);
  cvt16s<<<cgrid((size_t)2048*EMBP),256,0,stream>>>(WihR, wihR_h, 2048, EMBD, EMBD, EMBP);
  cvt16s<<<cgrid((size_t)2048*EH),256,0,stream>>>(WhhF, whhF_h, 2048, EH, EH, EH);
  cvt16s<<<cgrid((size_t)2048*EH),256,0,stream>>>(WhhR, whhR_h, 2048, EH, EH, EH);
  cvt16s<<<cgrid((size_t)1024*DH),256,0,stream>>>(wi, wm1_h, 1024, DH, DH, DH);
  cvt16s<<<cgrid((size_t)4096*DH),256,0,stream>>>(dWhh, wm1_h + (size_t)1024*DH, 4096, DH, DH, DH);
  cvt16s<<<cgrid((size_t)DH*2048),256,0,stream>>>(wo, wo_h, DH, 2048, 2048, 2048);
  cvt16s<<<cgrid((size_t)4096*DH),256,0,stream>>>(dWih, w3c, 4096, 1324, 1024, 1024);
  cvt16s<<<cgrid((size_t)4096*EMBP),256,0,stream>>>(dWih + 1024, w3pe, 4096, 1324, 300, EMBP);
  cvt16s<<<cgrid((size_t)GV*DH),256,0,stream>>>(genw, genw_h, GV, DH, DH, DH);
  addb<<<cgrid(2048),256,0,stream>>>(bihF, bhhF, b4f, 2048);
  addb<<<cgrid(2048),256,0,stream>>>(bihR, bhhR, b4r, 2048);
  addb<<<cgrid(4096),256,0,stream>>>(dbih, dbhh, db4, 4096);
  k_embed<<<cgrid((size_t)(TSRC+TDEC)*NB*EMBP),256,0,stream>>>(src, trg, eemb, demb, x_h, xrev_h, pe_h);

  // --- encoder input projections (bias folded in) + pe projection for decoder ---
  gemm128<<<dim3(16,25),256,0,stream>>>(x_h,    EMBP, wihF_h, EMBP, b4f, xp_f, 2048, EMBP, 3200, 2048, 0);
  gemm128<<<dim3(16,25),256,0,stream>>>(xrev_h, EMBP, wihR_h, EMBP, b4r, xp_r, 2048, EMBP, 3200, 2048, 0);
  gemm128<<<dim3(32,25),256,0,stream>>>(pe_h, EMBP, w3pe, EMBP, db4, peproj, 4096, EMBP, 3136, 4096, 0);

  // --- persistent weight-stationary sequential kernel ---
  SA sa;
  sa.whhF = whhF_h; sa.whhR = whhR_h;
  sa.wm1 = wm1_h;
  sa.wo = wo_h;
  sa.w3c = w3c;
  sa.xpF = xp_f; sa.xpR = xp_r;
  sa.pp = peproj;
  sa.h = hbuf;
  sa.cF = cf; sa.cR = cr;
  sa.enc_out = enc_out;
  sa.dh = dh; sa.dc = dc;
  sa.q = qb; sa.gh = gh;
  sa.st = st; sa.ct = ct;
  sa.gates4 = gates4;
  sa.hdec = hdec;
  sa.bar = bar;
  hipFuncSetAttribute((const void*)seq_kernel,
                      hipFuncAttributeMaxDynamicSharedMemorySize, LDS_TOT);
  seq_kernel<<<dim3(GRIDN), 256, LDS_TOT, stream>>>(sa);

  // --- generator: logits into d_out rows 64.. (t+1 shift), then log-softmax ---
  gemm128<<<dim3(GVP/128,25),256,0,stream>>>(hdec, DH, genw_h, DH, genb, out, GV, DH, 3136, GV, NB);
  lsm<<<3136,256,0,stream>>>(out);
}

// Round 7
// 6218.931 us; speedup vs baseline: 6.5273x; 1.0167x over previous
//
#include <hip/hip_runtime.h>
#include <cstdint>
#include <cmath>

// ---------------- dims ----------------
#define NB    64      // batch
#define EMBD  300
#define EMBP  320     // padded K for embedding-side GEMMs
#define EH    512     // encoder hidden
#define DH    1024    // decoder hidden
#define GV    23262   // target vocab
#define GVP   23296   // padded to 182*128
#define TSRC  50
#define TDEC  49      // decoder steps
#define GRIDN 248     // persistent WGs (1 WG/CU due to LDS)
#define NUNITS 416    // 64 enc + 160 P1 + 64 P3 + 128 P4 (64 KB weight units)
#define LDS_SCR 131072            // scratch region offset (after 2x64KB weight slots)
#define LDS_TOT (131072 + 16384)  // 144 KB dynamic LDS per WG
#define BARI  320     // ints per barrier object (8 leaves*32 + root@256 + gen@288)

typedef __attribute__((ext_vector_type(8))) _Float16 f16x8;
typedef __attribute__((ext_vector_type(4))) float f32x4;

__device__ __forceinline__ float sigm(float x){ return 1.f/(1.f+expf(-x)); }

// ---- device-coherent (agent-scope, cache-bypassing) access helpers ----
__device__ __forceinline__ f16x8 cohA16(const _Float16* p){
  union { unsigned long long u[2]; f16x8 v; } x;
  x.u[0] = __hip_atomic_load((const unsigned long long*)p,     __ATOMIC_RELAXED, __HIP_MEMORY_SCOPE_AGENT);
  x.u[1] = __hip_atomic_load((const unsigned long long*)p + 1, __ATOMIC_RELAXED, __HIP_MEMORY_SCOPE_AGENT);
  return x.v;
}
__device__ __forceinline__ void cohS16(_Float16* p, _Float16 v){
  union { _Float16 f; unsigned short u; } c; c.f = v;
  __hip_atomic_store((unsigned short*)p, c.u, __ATOMIC_RELAXED, __HIP_MEMORY_SCOPE_AGENT);
}
__device__ __forceinline__ void cohS32(float* p, float v){
  __hip_atomic_store(p, v, __ATOMIC_RELAXED, __HIP_MEMORY_SCOPE_AGENT);
}
__device__ __forceinline__ float cohL32(const float* p){
  return __hip_atomic_load(p, __ATOMIC_RELAXED, __HIP_MEMORY_SCOPE_AGENT);
}

// ---- tree barrier: relaxed-only, no cache maintenance. ----
// Leaves by wgid>>5 (targets packed 6b/group); root@256, gen@288 (separate lines).
__device__ __forceinline__ void barArrive(int* bb, unsigned long long tgt, int nleaf, int epoch)
{
  __syncthreads();   // drains each wave's outstanding (coherent) stores
  if (threadIdx.x == 0) {
    int g = (int)(blockIdx.x >> 5);
    int t = (int)((tgt >> (g*6)) & 63ull);
    int* leaf = bb + g*32;
    int v = __hip_atomic_fetch_add(leaf, 1, __ATOMIC_RELAXED, __HIP_MEMORY_SCOPE_AGENT);
    if (v == t - 1) {
      __hip_atomic_store(leaf, 0, __ATOMIC_RELAXED, __HIP_MEMORY_SCOPE_AGENT);
      int r = __hip_atomic_fetch_add(bb + 256, 1, __ATOMIC_RELAXED, __HIP_MEMORY_SCOPE_AGENT);
      if (r == nleaf - 1) {
        __hip_atomic_store(bb + 256, 0, __ATOMIC_RELAXED, __HIP_MEMORY_SCOPE_AGENT);
        __hip_atomic_store(bb + 288, epoch, __ATOMIC_RELAXED, __HIP_MEMORY_SCOPE_AGENT);
      }
    }
  }
}
__device__ __forceinline__ void barWait(int* bb, int epoch)
{
  if (threadIdx.x == 0) {
    while (__hip_atomic_load(bb + 288, __ATOMIC_RELAXED, __HIP_MEMORY_SCOPE_AGENT) < epoch)
      __builtin_amdgcn_s_sleep(1);
    __atomic_signal_fence(__ATOMIC_SEQ_CST);  // no compiler hoist of data loads
  }
  __syncthreads();
}

// ---- stage a [nrows][ncols] fp16 tile into LDS with XOR-16B swizzle ----
__device__ __forceinline__ void stageW(char* dst, const _Float16* __restrict__ src,
                                       int srcld, int nrows, int ncols, int tid)
{
  const int nch = ncols >> 3;
  for (int i = tid; i < nrows*nch; i += 256) {
    int row = i / nch, c = i - row*nch;
    *(f16x8*)(dst + row*ncols*2 + ((c*16) ^ ((row&7)<<4))) =
        *(const f16x8*)(src + (size_t)row*srcld + c*8);
  }
}

// 64x16 MFMA tile, K=512: acc += A[64][K](coherent global fp16) @ B[16][K](LDS)^T.
template<int K>
__device__ __forceinline__ void mm16C(f32x4 (&acc)[4],
    const _Float16* __restrict__ A, int lda,
    const char* ldsB, int rowbytes, int koffB, int lane)
{
  const int r = lane & 15, q = lane >> 4;
  const _Float16* a0 = A + r*lda + q*8;
  const char* b0 = ldsB + r*rowbytes + koffB;
  const int sw = (r & 7) << 4;
#pragma unroll
  for (int g = 0; g < K/128; ++g) {
    f16x8 av[4][4], bv[4];
#pragma unroll
    for (int s = 0; s < 4; ++s) {
      int sl = g*4 + s;
      bv[s] = *(const f16x8*)(b0 + ((sl*64 + q*16) ^ sw));
#pragma unroll
      for (int m = 0; m < 4; ++m)
        av[s][m] = cohA16(a0 + m*16*lda + sl*32);
    }
#pragma unroll
    for (int s = 0; s < 4; ++s)
#pragma unroll
      for (int m = 0; m < 4; ++m)
        acc[m] = __builtin_amdgcn_mfma_f32_16x16x32_f16(av[s][m], bv[s], acc[m], 0, 0, 0);
  }
}

// ---------------- prep kernels ----------------
__global__ void cvt16s(const float* __restrict__ src, _Float16* __restrict__ dst,
                       int rows, int sld, int scols, int dcols)
{
  int idx = blockIdx.x*256 + threadIdx.x;
  if (idx >= rows*dcols) return;
  int c = idx % dcols, rr = idx / dcols;
  dst[idx] = (c < scols) ? (_Float16)src[(size_t)rr*sld + c] : (_Float16)0.f;
}

__global__ void addb(const float* __restrict__ a, const float* __restrict__ b,
                     float* __restrict__ o, int n)
{
  int i = blockIdx.x*256 + threadIdx.x;
  if (i < n) o[i] = a[i] + b[i];
}

__global__ void k_embed(const int* __restrict__ src, const int* __restrict__ trg,
                        const float* __restrict__ eemb, const float* __restrict__ demb,
                        _Float16* __restrict__ x_h, _Float16* __restrict__ xrev_h,
                        _Float16* __restrict__ pe_h)
{
  int idx = blockIdx.x*256 + threadIdx.x;
  const int tot1 = TSRC*NB*EMBP;
  const int tot2 = TDEC*NB*EMBP;
  if (idx < tot1) {
    int e = idx % EMBP, rb = idx / EMBP;
    int t = rb >> 6, b = rb & 63;
    float v = 0.f;
    if (e < EMBD) v = eemb[(size_t)src[rb]*EMBD + e];
    _Float16 hv = (_Float16)v;
    x_h[idx] = hv;
    xrev_h[(size_t)((TSRC-1-t)*NB + b)*EMBP + e] = hv;
  } else if (idx < tot1 + tot2) {
    int k = idx - tot1;
    int e = k % EMBP, rb = k / EMBP;
    float v = 0.f;
    if (e < EMBD) v = demb[(size_t)trg[rb]*EMBD + e];
    pe_h[k] = (_Float16)v;
  }
}

// ---------------- big tiled GEMM (throughput path), fp16 ----------------
__global__ __launch_bounds__(256) void gemm128(
    const _Float16* __restrict__ A, int lda,
    const _Float16* __restrict__ W, int ldw,
    const float* __restrict__ bias,
    float* __restrict__ out, int ldo,
    int K, int mvalid, int nvalid, int rowoff)
{
  __shared__ _Float16 As[128*64];
  __shared__ _Float16 Bs[128*64];
  const int tid = threadIdx.x;
  const int m0 = blockIdx.y*128, n0 = blockIdx.x*128;
  const int w = tid >> 6, lane = tid & 63, r = lane & 15, q = lane >> 4;
  const int mw = (w >> 1)*64, nw = (w & 1)*64;
  f32x4 acc[4][4];
#pragma unroll
  for (int mi=0; mi<4; ++mi)
#pragma unroll
    for (int ni=0; ni<4; ++ni) acc[mi][ni] = 0.f;

  for (int kt = 0; kt < K; kt += 64) {
    f16x8 ra[4], rb[4];
#pragma unroll
    for (int j = 0; j < 4; ++j) {
      int c = j*256 + tid, row = c >> 3, cc = c & 7;
      ra[j] = *(const f16x8*)(A + (size_t)(m0+row)*lda + kt + cc*8);
      rb[j] = *(const f16x8*)(W + (size_t)(n0+row)*ldw + kt + cc*8);
    }
    __syncthreads();
#pragma unroll
    for (int j = 0; j < 4; ++j) {
      int c = j*256 + tid, row = c >> 3, cc = c & 7;
      int sw = cc ^ (row & 7);
      *(f16x8*)((char*)As + row*128 + (sw<<4)) = ra[j];
      *(f16x8*)((char*)Bs + row*128 + (sw<<4)) = rb[j];
    }
    __syncthreads();
#pragma unroll
    for (int kk = 0; kk < 64; kk += 32) {
      int ch = (kk >> 3) + q;
      f16x8 av[4], bv[4];
#pragma unroll
      for (int mi=0; mi<4; ++mi) {
        int row = mw + mi*16 + r;
        av[mi] = *(const f16x8*)((char*)As + row*128 + ((ch ^ (row&7))<<4));
      }
#pragma unroll
      for (int ni=0; ni<4; ++ni) {
        int row = nw + ni*16 + r;
        bv[ni] = *(const f16x8*)((char*)Bs + row*128 + ((ch ^ (row&7))<<4));
      }
#pragma unroll
      for (int mi=0; mi<4; ++mi)
#pragma unroll
        for (int ni=0; ni<4; ++ni)
          acc[mi][ni] = __builtin_amdgcn_mfma_f32_16x16x32_f16(av[mi], bv[ni], acc[mi][ni], 0,0,0);
    }
  }
#pragma unroll
  for (int mi=0; mi<4; ++mi)
#pragma unroll
    for (int ni=0; ni<4; ++ni)
#pragma unroll
      for (int e=0; e<4; ++e) {
        int mrow = m0 + mw + mi*16 + q*4 + e;
        int col  = n0 + nw + ni*16 + r;
        if (mrow < mvalid && col < nvalid)
          out[(size_t)(mrow + rowoff)*ldo + col] = acc[mi][ni][e] + bias[col];
      }
}

// ---------------- persistent weight-stationary sequential kernel ----------------
struct SA {
  const _Float16 *whhF, *whhR;   // [2048][512]
  const _Float16 *wm1;           // [5120][1024]
  const _Float16 *wo;            // [1024][2048]
  const _Float16 *w3c;           // [4096][1024]
  const float *xpF, *xpR;        // [50*64][2048] (bias included)
  const float *pp;               // [49*64][4096] pe@dWih_pe + biases
  _Float16 *h;                   // [2 dir][2 buf][64][512]   (coherent)
  float *cF, *cR;                // [64][512]                 (WG-private, cached)
  _Float16 *enc_out;             // [50][64][1024]  (coh-written, cached-read in decoder)
  _Float16 *dh;                  // [64][1024]  (coherent)
  float *dc;                     // [64][1024]  (coherent)
  float *q;                      // [64][1024]  (coherent)
  float *gh;                     // [64][4096]  (coherent)
  _Float16 *st, *ct;             // [64][1024]  (coherent)
  _Float16 *hdec;                // [3200][1024] (plain, read by next kernel)
  int *bar;                      // 6 barrier objects
};

__global__ __launch_bounds__(256, 1) void seq_kernel(SA a)
{
  extern __shared__ char lds[];
  const int tid = threadIdx.x, w = tid >> 6, lane = tid & 63;
  const int wgid = blockIdx.x;
  const int r = lane & 15, q4 = lane >> 4;
  float (*sm4)[64][16] = (float(*)[64][16])(lds + LDS_SCR);
  float* qs = (float*)(lds + LDS_SCR);          // P2 only (aliases sm4)
  float* sc = (float*)(lds + LDS_SCR + 4096);

  // ---- stage this WG's weight units into LDS (once) ----
  for (int s = 0; s < 2; ++s) {
    int u = wgid + s*GRIDN;
    if (u >= NUNITS) break;
    char* dst = lds + s*65536;
    if (u < 64) {
      int dir = u >> 5, j0 = (u & 31) << 4;
      const _Float16* whh = dir ? a.whhR : a.whhF;
      for (int g = 0; g < 4; ++g)
        stageW(dst + g*16384, whh + (size_t)(g*EH + j0)*EH, EH, 16, 512, tid);
    } else if (u < 224) {
      stageW(dst, a.wm1 + (size_t)(u-64)*32*DH, DH, 32, 1024, tid);
    } else if (u < 288) {
      stageW(dst, a.wo + (size_t)(u-224)*16*2048, 2048, 16, 2048, tid);
    } else {
      // P4 fused: gate-interleaved rows {g*1024 + j0 + 0..7}, g=0..3
      int i = u - 288, j0 = i*8;
      for (int g = 0; g < 4; ++g)
        stageW(dst + g*8*2048, a.w3c + (size_t)(g*1024 + j0)*DH, DH, 8, 1024, tid);
    }
  }
  __syncthreads();

  int* barEF = a.bar + 0*BARI;
  int* barER = a.bar + 1*BARI;
  int* barA  = a.bar + 2*BARI;
  int* barB  = a.bar + 3*BARI;
  int* barC  = a.bar + 4*BARI;
  int* barD  = a.bar + 5*BARI;
  const unsigned long long TEF = 32ull;
  const unsigned long long TER = 32ull << 6;
  const unsigned long long TA  = (32ull<<12)|(32ull<<18)|(32ull<<24)|(32ull<<30)|(32ull<<36);
  const unsigned long long TB  = 32ull | (32ull<<6);
  const unsigned long long TC  = 32ull | (8ull<<6) | (24ull<<42);
  const unsigned long long TD  = (24ull<<6)|(32ull<<12)|(32ull<<18)|(32ull<<24)|(8ull<<30);

  const bool isEnc = (wgid < 64);
  const bool isP1  = (wgid >= 64 && wgid < 224);
  const bool isP2  = (wgid < 64);
  const bool isP3  = (wgid < 40) || (wgid >= 224);
  const bool isP4  = (wgid >= 40 && wgid < 168);

  // ================= encoder: 50 steps (WGs 0-63; fwd/rev independent) =================
  if (isEnc) {
    const int dir = wgid >> 5, j0 = (wgid & 31) << 4;
    int* myE = dir ? barER : barEF;
    const unsigned long long myT = dir ? TER : TEF;
    for (int t = 0; t < TSRC; ++t) {
      if (t) barWait(myE, t);
      const int cur = t & 1;
      const _Float16* H = a.h + (size_t)(dir*2 + cur)*NB*EH;
      f32x4 acc[4];
#pragma unroll
      for (int m=0;m<4;++m) acc[m] = 0.f;
      mm16C<EH>(acc, H, EH, lds + w*16384, 1024, 0, lane);
#pragma unroll
      for (int m=0;m<4;++m)
#pragma unroll
        for (int e=0;e<4;++e) sm4[w][m*16 + q4*4 + e][r] = acc[m][e];
      __syncthreads();
      const float* xp = (dir ? a.xpR : a.xpF) + (size_t)t*NB*2048;
      float* C = dir ? a.cR : a.cF;
      _Float16* Ho = a.h + (size_t)(dir*2 + (cur^1))*NB*EH;
      const int erow = dir ? (TSRC-1 - t) : t;
      for (int p = tid; p < 1024; p += 256) {
        int b = p >> 4, jj = p & 15, j = j0 + jj;
        float gi = sm4[0][b][jj] + xp[b*2048 + 0*EH + j];
        float gf = sm4[1][b][jj] + xp[b*2048 + 1*EH + j];
        float gg = sm4[2][b][jj] + xp[b*2048 + 2*EH + j];
        float go = sm4[3][b][jj] + xp[b*2048 + 3*EH + j];
        float co = C[b*EH + j];
        float cn = sigm(gf)*co + sigm(gi)*tanhf(gg);
        float hn = sigm(go)*tanhf(cn);
        C[b*EH + j] = cn;
        _Float16 hb = (_Float16)hn;
        cohS16(Ho + b*EH + j, hb);
        cohS16(a.enc_out + ((size_t)erow*NB + b)*DH + dir*EH + j, hb);
        if (t == TSRC-1) {
          cohS16(a.dh + b*DH + 2*j + dir, hb);
          cohS32(a.dc + b*DH + 2*j + dir, cn);
        }
      }
      barArrive(myE, myT, 1, t+1);
    }
  }

  // ================= decoder: 49 steps =================
  for (int t = 0; t < TDEC; ++t) {
    // ---- P1 (WGs 64-223): q|gh = dh @ [wi ; dWhh]^T ----
    if (isP1) {
      if (t == 0) { barWait(barEF, TSRC); barWait(barER, TSRC); }
      else        barWait(barD, t);
      const int col0 = (wgid - 64)*32;
      const int cs = w >> 1, kh = w & 1;
      f32x4 acc[4];
#pragma unroll
      for (int m=0;m<4;++m) acc[m] = 0.f;
      mm16C<512>(acc, a.dh + kh*512, DH, lds + cs*16*2048, 2048, kh*1024, lane);
#pragma unroll
      for (int m=0;m<4;++m)
#pragma unroll
        for (int e=0;e<4;++e) sm4[w][m*16 + q4*4 + e][r] = acc[m][e];
      __syncthreads();
      for (int p = tid; p < 2048; p += 256) {
        int b = p >> 5, cc = p & 31;
        float v = sm4[(cc>>4)*2][b][cc&15] + sm4[(cc>>4)*2 + 1][b][cc&15];
        int C = col0 + cc;
        if (C < 1024) cohS32(a.q + b*DH + C, v);
        else          cohS32(a.gh + (size_t)b*4096 + C - 1024, v);
      }
      barArrive(barA, TA, 5, t+1);
    }

    // ---- P2 (WGs 0-63): attention, one batch element each ----
    if (isP2) {
      barWait(barA, t+1);
      const int b = wgid;
      for (int i = tid; i < 1024; i += 256) qs[i] = cohL32(a.q + b*DH + i);
      __syncthreads();
      for (int tt = w; tt < TSRC; tt += 4) {
        const _Float16* er = a.enc_out + ((size_t)tt*NB + b)*DH + lane*16;
        const float* qq = qs + lane*16;
        f16x8 e0 = *(const f16x8*)(er);
        f16x8 e1 = *(const f16x8*)(er + 8);
        float s = 0.f;
#pragma unroll
        for (int ii=0; ii<8; ++ii) s += (float)e0[ii]*qq[ii];
#pragma unroll
        for (int ii=0; ii<8; ++ii) s += (float)e1[ii]*qq[8+ii];
#pragma unroll
        for (int o=32; o; o>>=1) s += __shfl_xor(s, o);
        if (lane == 0) sc[tt] = s;
      }
      __syncthreads();
      float mx = -1e30f;
      for (int tt=0; tt<TSRC; ++tt) mx = fmaxf(mx, sc[tt]);
      __syncthreads();
      if (tid < TSRC) sc[tid] = expf(sc[tid] - mx);
      __syncthreads();
      float s50 = 0.f;
      for (int tt=0; tt<TSRC; ++tt) s50 += sc[tt];
      const float inv = 1.f/s50;
      const int c0 = tid*4;
      float a0=0.f, a1=0.f, a2=0.f, a3=0.f;
      for (int tt=0; tt<TSRC; ++tt) {
        float wt = sc[tt];
        const _Float16* er = a.enc_out + ((size_t)tt*NB + b)*DH + c0;
        a0 += wt*(float)er[0]; a1 += wt*(float)er[1];
        a2 += wt*(float)er[2]; a3 += wt*(float)er[3];
      }
      cohS16(a.st + b*DH + c0 + 0, (_Float16)(a0*inv));
      cohS16(a.st + b*DH + c0 + 1, (_Float16)(a1*inv));
      cohS16(a.st + b*DH + c0 + 2, (_Float16)(a2*inv));
      cohS16(a.st + b*DH + c0 + 3, (_Float16)(a3*inv));
      barArrive(barB, TB, 2, t+1);
    }

    // ---- P3 (WGs 224-247 slot0 + 0-39 slot1): ct = tanh([st,dh] @ wo^T) ----
    if (isP3) {
      barWait(barB, t+1);
      const bool p0 = (wgid >= 224);
      const int idx  = p0 ? (wgid - 224) : (wgid + 24);
      const char* ldsB = lds + (p0 ? 0 : 65536);
      const int col0 = idx*16;
      const _Float16* A = (w < 2 ? a.st : a.dh) + (w & 1)*512;
      f32x4 acc[4];
#pragma unroll
      for (int m=0;m<4;++m) acc[m] = 0.f;
      mm16C<512>(acc, A, DH, ldsB, 4096, w*1024, lane);
#pragma unroll
      for (int m=0;m<4;++m)
#pragma unroll
        for (int e=0;e<4;++e) sm4[w][m*16 + q4*4 + e][r] = acc[m][e];
      __syncthreads();
      for (int p = tid; p < 1024; p += 256) {
        int b = p >> 4, jj = p & 15;
        float v = sm4[0][b][jj] + sm4[1][b][jj] + sm4[2][b][jj] + sm4[3][b][jj];
        cohS16(a.ct + b*DH + col0 + jj, (_Float16)tanhf(v));
      }
      barArrive(barC, TC, 3, t+1);
    }

    // ---- P4 (WGs 40-167): fused gates matmul + LSTM update (8 j-cols, all 4 gates) ----
    if (isP4) {
      barWait(barC, t+1);
      const int j0 = (wgid - 40)*8;
      const int cs = w >> 1, kh = w & 1;
      f32x4 acc[4];
#pragma unroll
      for (int m=0;m<4;++m) acc[m] = 0.f;
      mm16C<512>(acc, a.ct + kh*512, DH, lds + 65536 + cs*16*2048, 2048, kh*1024, lane);
#pragma unroll
      for (int m=0;m<4;++m)
#pragma unroll
        for (int e=0;e<4;++e) sm4[w][m*16 + q4*4 + e][r] = acc[m][e];
      __syncthreads();
      const float* pp = a.pp + (size_t)t*NB*4096;
      for (int p = tid; p < 512; p += 256) {
        int b = p >> 3, jj = p & 7, j = j0 + jj;
        float g0 = sm4[0][b][jj]      + sm4[1][b][jj];
        float g1 = sm4[0][b][8+jj]    + sm4[1][b][8+jj];
        float g2 = sm4[2][b][jj]      + sm4[3][b][jj];
        float g3 = sm4[2][b][8+jj]    + sm4[3][b][8+jj];
        float gi = g0 + cohL32(a.gh + (size_t)b*4096 + 0*DH + j) + pp[(size_t)b*4096 + 0*DH + j];
        float gf = g1 + cohL32(a.gh + (size_t)b*4096 + 1*DH + j) + pp[(size_t)b*4096 + 1*DH + j];
        float gg = g2 + cohL32(a.gh + (size_t)b*4096 + 2*DH + j) + pp[(size_t)b*4096 + 2*DH + j];
        float go = g3 + cohL32(a.gh + (size_t)b*4096 + 3*DH + j) + pp[(size_t)b*4096 + 3*DH + j];
        float co = cohL32(a.dc + b*DH + j);
        float cn = sigm(gf)*co + sigm(gi)*tanhf(gg);
        float hn = sigm(go)*tanhf(cn);
        cohS32(a.dc + b*DH + j, cn);
        _Float16 hb = (_Float16)hn;
        cohS16(a.dh + b*DH + j, hb);
        a.hdec[((size_t)t*NB + b)*DH + j] = hb;
      }
      barArrive(barD, TD, 5, t+1);
    }
  }
}

// ---------------- in-place log-softmax over vocab rows ----------------
__global__ __launch_bounds__(256) void lsm(float* __restrict__ out)
{
  const int row = NB + blockIdx.x;  // rows 64..3199
  float* p = out + (size_t)row*GV;
  const int tid = threadIdx.x;
  __shared__ float red[4], red2[4];
  float mx = -1e30f;
  for (int i = tid; i < GV; i += 256) mx = fmaxf(mx, p[i]);
  for (int off=32; off; off>>=1) mx = fmaxf(mx, __shfl_down(mx, off));
  if ((tid & 63) == 0) red[tid>>6] = mx;
  __syncthreads();
  mx = fmaxf(fmaxf(red[0],red[1]), fmaxf(red[2],red[3]));
  float sm = 0.f;
  for (int i = tid; i < GV; i += 256) sm += expf(p[i] - mx);
  for (int off=32; off; off>>=1) sm += __shfl_down(sm, off);
  if ((tid & 63) == 0) red2[tid>>6] = sm;
  __syncthreads();
  sm = red2[0]+red2[1]+red2[2]+red2[3];
  float lse = mx + logf(sm);
  for (int i = tid; i < GV; i += 256) p[i] -= lse;
}

// ---------------- host ----------------
extern "C" void kernel_launch(void* const* d_in, const int* in_sizes, int n_in,
                              void* d_out, int out_size, void* d_ws, size_t ws_size,
                              hipStream_t stream)
{
  const int*   src  = (const int*)d_in[0];
  const int*   trg  = (const int*)d_in[1];
  const float* WihF = (const float*)d_in[2];
  const float* WhhF = (const float*)d_in[3];
  const float* bihF = (const float*)d_in[4];
  const float* bhhF = (const float*)d_in[5];
  const float* WihR = (const float*)d_in[6];
  const float* WhhR = (const float*)d_in[7];
  const float* bihR = (const float*)d_in[8];
  const float* bhhR = (const float*)d_in[9];
  const float* dWih = (const float*)d_in[10];
  const float* dWhh = (const float*)d_in[11];
  const float* dbih = (const float*)d_in[12];
  const float* dbhh = (const float*)d_in[13];
  const float* eemb = (const float*)d_in[14];
  const float* demb = (const float*)d_in[15];
  const float* wi   = (const float*)d_in[16];
  const float* wo   = (const float*)d_in[17];
  const float* genw = (const float*)d_in[18];
  const float* genb = (const float*)d_in[19];
  float* out = (float*)d_out;

  char* ws = (char*)d_ws;
  size_t off = 0;
  auto alloc = [&](size_t bytes)->char* {
    char* p = ws + off; off = (off + bytes + 255) & ~(size_t)255; return p;
  };
  _Float16* x_h    = (_Float16*)alloc((size_t)TSRC*NB*EMBP*2);
  _Float16* xrev_h = (_Float16*)alloc((size_t)TSRC*NB*EMBP*2);
  _Float16* pe_h   = (_Float16*)alloc((size_t)TDEC*NB*EMBP*2);
  _Float16* wihF_h = (_Float16*)alloc((size_t)2048*EMBP*2);
  _Float16* wihR_h = (_Float16*)alloc((size_t)2048*EMBP*2);
  _Float16* whhF_h = (_Float16*)alloc((size_t)2048*EH*2);
  _Float16* whhR_h = (_Float16*)alloc((size_t)2048*EH*2);
  _Float16* wm1_h  = (_Float16*)alloc((size_t)5120*DH*2);
  _Float16* wo_h   = (_Float16*)alloc((size_t)DH*2048*2);
  _Float16* w3c    = (_Float16*)alloc((size_t)4096*DH*2);
  _Float16* w3pe   = (_Float16*)alloc((size_t)4096*EMBP*2);
  _Float16* genw_h = (_Float16*)alloc((size_t)GVP*DH*2);
  float* b4f   = (float*)alloc(2048*4);
  float* b4r   = (float*)alloc(2048*4);
  float* db4   = (float*)alloc(4096*4);
  float* xp_f  = (float*)alloc((size_t)TSRC*NB*2048*4);
  float* xp_r  = (float*)alloc((size_t)TSRC*NB*2048*4);
  float* peproj = (float*)alloc((size_t)TDEC*NB*4096*4);
  _Float16* enc_out = (_Float16*)alloc((size_t)TSRC*NB*DH*2);
  _Float16* hbuf = (_Float16*)alloc((size_t)4*NB*EH*2);
  float* cf = (float*)alloc((size_t)NB*EH*4);
  float* cr = (float*)alloc((size_t)NB*EH*4);
  _Float16* dh = (_Float16*)alloc((size_t)NB*DH*2);
  float* dc = (float*)alloc((size_t)NB*DH*4);
  float* qb = (float*)alloc((size_t)NB*DH*4);
  float* gh = (float*)alloc((size_t)NB*4096*4);
  _Float16* st = (_Float16*)alloc((size_t)NB*DH*2);
  _Float16* ct = (_Float16*)alloc((size_t)NB*DH*2);
  _Float16* hdec = (_Float16*)alloc((size_t)3200*DH*2);
  int* bar = (int*)alloc(6*BARI*4);
  (void)in_sizes; (void)n_in; (void)out_size; (void)ws_size;

  // --- init / zero state (every call: graph replays don't re-poison) ---
  hipMemsetAsync(hbuf, 0, (size_t)4*NB*EH*2, stream);
  hipMemsetAsync(cf, 0, (size_t)NB*EH*4, stream);
  hipMemsetAsync(cr, 0, (size_t)NB*EH*4, stream);
  hipMemsetAsync(hdec + (size_t)3136*DH, 0, (size_t)64*DH*2, stream);
  hipMemsetAsync(genw_h + (size_t)GV*DH, 0, (size_t)(GVP-GV)*DH*2, stream);
  hipMemsetAsync(out, 0, (size_t)NB*GV*4, stream);   // timestep 0 = zeros
  hipMemsetAsync(bar, 0, 6*BARI*4, stream);

  auto cgrid = [](size_t n){ return dim3((unsigned)((n + 255)/256)); };

  // --- weight conversion (fp16) ---
  cvt16s<<<cgrid((size_t)2048*EMBP),256,0,stream>>>(WihF, wihF_h, 2048, EMBD, EMBD, EMBP);
  cvt16s<<<cgrid((size_t)2048*EMBP),256,0,stream>>>(WihR, wihR_h, 2048, EMBD, EMBD, EMBP);
  cvt16s<<<cgrid((size_t)2048*EH),256,0,stream>>>(WhhF, whhF_h, 2048, EH, EH, EH);
  cvt16s<<<cgrid((size_t)2048*EH),256,0,stream>>>(WhhR, whhR_h, 2048, EH, EH, EH);
  cvt16s<<<cgrid((size_t)1024*DH),256,0,stream>>>(wi, wm1_h, 1024, DH, DH, DH);
  cvt16s<<<cgrid((size_t)4096*DH),256,0,stream>>>(dWhh, wm1_h + (size_t)1024*DH, 4096, DH, DH, DH);
  cvt16s<<<cgrid((size_t)DH*2048),256,0,stream>>>(wo, wo_h, DH, 2048, 2048, 2048);
  cvt16s<<<cgrid((size_t)4096*DH),256,0,stream>>>(dWih, w3c, 4096, 1324, 1024, 1024);
  cvt16s<<<cgrid((size_t)4096*EMBP),256,0,stream>>>(dWih + 1024, w3pe, 4096, 1324, 300, EMBP);
  cvt16s<<<cgrid((size_t)GV*DH),256,0,stream>>>(genw, genw_h, GV, DH, DH, DH);
  addb<<<cgrid(2048),256,0,stream>>>(bihF, bhhF, b4f, 2048);
  addb<<<cgrid(2048),256,0,stream>>>(bihR, bhhR, b4r, 2048);
  addb<<<cgrid(4096),256,0,stream>>>(dbih, dbhh, db4, 4096);
  k_embed<<<cgrid((size_t)(TSRC+TDEC)*NB*EMBP),256,0,stream>>>(src, trg, eemb, demb, x_h, xrev_h, pe_h);

  // --- encoder input projections (bias folded in) + pe projection for decoder ---
  gemm128<<<dim3(16,25),256,0,stream>>>(x_h,    EMBP, wihF_h, EMBP, b4f, xp_f, 2048, EMBP, 3200, 2048, 0);
  gemm128<<<dim3(16,25),256,0,stream>>>(xrev_h, EMBP, wihR_h, EMBP, b4r, xp_r, 2048, EMBP, 3200, 2048, 0);
  gemm128<<<dim3(32,25),256,0,stream>>>(pe_h, EMBP, w3pe, EMBP, db4, peproj, 4096, EMBP, 3136, 4096, 0);

  // --- persistent weight-stationary sequential kernel ---
  SA sa;
  sa.whhF = whhF_h; sa.whhR = whhR_h;
  sa.wm1 = wm1_h;
  sa.wo = wo_h;
  sa.w3c = w3c;
  sa.xpF = xp_f; sa.xpR = xp_r;
  sa.pp = peproj;
  sa.h = hbuf;
  sa.cF = cf; sa.cR = cr;
  sa.enc_out = enc_out;
  sa.dh = dh; sa.dc = dc;
  sa.q = qb; sa.gh = gh;
  sa.st = st; sa.ct = ct;
  sa.hdec = hdec;
  sa.bar = bar;
  hipFuncSetAttribute((const void*)seq_kernel,
                      hipFuncAttributeMaxDynamicSharedMemorySize, LDS_TOT);
  seq_kernel<<<dim3(GRIDN), 256, LDS_TOT, stream>>>(sa);

  // --- generator: logits into d_out rows 64.. (t+1 shift), then log-softmax ---
  gemm128<<<dim3(GVP/128,25),256,0,stream>>>(hdec, DH, genw_h, DH, genb, out, GV, DH, 3136, GV, NB);
  lsm<<<3136,256,0,stream>>>(out);
}

// Round 8
// 3609.496 us; speedup vs baseline: 11.2461x; 1.7229x over previous
//
#include <hip/hip_runtime.h>
#include <cstdint>
#include <cmath>

// ---------------- dims ----------------
#define NB    64      // batch
#define EMBD  300
#define EMBP  320     // padded K for embedding-side GEMMs
#define EH    512     // encoder hidden
#define DH    1024    // decoder hidden
#define GV    23262   // target vocab
#define GVP   23296   // padded to 182*128
#define TSRC  50
#define TDEC  49      // decoder steps
#define GRIDN 248     // persistent WGs (1 WG/CU due to LDS)
#define NUNITS 416    // 64 enc + 160 P1 + 64 P3 + 128 P4 (64 KB weight units)
#define LDS_SCR 131072            // scratch region offset (after 2x64KB weight slots)
#define LDS_TOT (131072 + 16384)  // 144 KB dynamic LDS per WG
#define FSTRIDE 32    // ints between flags (128 B)

typedef __attribute__((ext_vector_type(8))) _Float16 f16x8;
typedef __attribute__((ext_vector_type(4))) float f32x4;

__device__ __forceinline__ float sigm(float x){ return 1.f/(1.f+expf(-x)); }

// ---- write-through stores (agent-scope relaxed atomics): all globally-visible
// kernel writes use these so L2 never holds dirty seq data (acquire-inv safe).
__device__ __forceinline__ void cohS16(_Float16* p, _Float16 v){
  union { _Float16 f; unsigned short u; } c; c.f = v;
  __hip_atomic_store((unsigned short*)p, c.u, __ATOMIC_RELAXED, __HIP_MEMORY_SCOPE_AGENT);
}
__device__ __forceinline__ void cohS32(float* p, float v){
  __hip_atomic_store(p, v, __ATOMIC_RELAXED, __HIP_MEMORY_SCOPE_AGENT);
}

// ---- flag barrier: producers post their own flag (no RMW); consumers poll
// assigned flags relaxed (bypasses L1/L2), then one acquire fence per WG
// invalidates L1/L2 so subsequent PLAIN loads see fresh data AND share L2
// within an XCD (the round-7 killer: atomic data loads bypassed L2 -> 20x traffic).
__device__ __forceinline__ void flagSet(int* flagArr, int wg, int epoch)
{
  __syncthreads();   // all waves' write-through stores drained (vmcnt=0 at barrier)
  if (threadIdx.x == 0)
    __hip_atomic_store(flagArr + wg*FSTRIDE, epoch, __ATOMIC_RELAXED, __HIP_MEMORY_SCOPE_AGENT);
}
__device__ __forceinline__ void flagWaitIdx(int* flagArr, int myIdx, bool active, int epoch)
{
  if (active) {
    int* p = flagArr + myIdx*FSTRIDE;
    while (__hip_atomic_load(p, __ATOMIC_RELAXED, __HIP_MEMORY_SCOPE_AGENT) < epoch)
      __builtin_amdgcn_s_sleep(8);
  }
  __syncthreads();
  if (threadIdx.x == 0) __builtin_amdgcn_fence(__ATOMIC_ACQUIRE, "agent");
  __syncthreads();
}

// ---- stage a [nrows][ncols] fp16 tile into LDS with XOR-16B swizzle ----
__device__ __forceinline__ void stageW(char* dst, const _Float16* __restrict__ src,
                                       int srcld, int nrows, int ncols, int tid)
{
  const int nch = ncols >> 3;
  for (int i = tid; i < nrows*nch; i += 256) {
    int row = i / nch, c = i - row*nch;
    *(f16x8*)(dst + row*ncols*2 + ((c*16) ^ ((row&7)<<4))) =
        *(const f16x8*)(src + (size_t)row*srcld + c*8);
  }
}

// 64x16 MFMA tile: acc += A[64][K](plain cached loads) @ B[16][K](LDS, swizzled)^T.
// 8 k-slices staged per group (~512 B/lane in flight; 1 wave/SIMD -> VGPRs cheap).
template<int K>
__device__ __forceinline__ void mm16L(f32x4 (&acc)[4],
    const _Float16* __restrict__ A, int lda,
    const char* ldsB, int rowbytes, int koffB, int lane)
{
  const int r = lane & 15, q = lane >> 4;
  const _Float16* a0 = A + r*lda + q*8;
  const char* b0 = ldsB + r*rowbytes + koffB;
  const int sw = (r & 7) << 4;
#pragma unroll
  for (int g = 0; g < K/256; ++g) {
    f16x8 av[8][4], bv[8];
#pragma unroll
    for (int s = 0; s < 8; ++s) {
      int sl = g*8 + s;
      bv[s] = *(const f16x8*)(b0 + ((sl*64 + q*16) ^ sw));
#pragma unroll
      for (int m = 0; m < 4; ++m)
        av[s][m] = *(const f16x8*)(a0 + m*16*lda + sl*32);
    }
#pragma unroll
    for (int s = 0; s < 8; ++s)
#pragma unroll
      for (int m = 0; m < 4; ++m)
        acc[m] = __builtin_amdgcn_mfma_f32_16x16x32_f16(av[s][m], bv[s], acc[m], 0, 0, 0);
  }
}

// ---------------- prep kernels ----------------
__global__ void cvt16s(const float* __restrict__ src, _Float16* __restrict__ dst,
                       int rows, int sld, int scols, int dcols)
{
  int idx = blockIdx.x*256 + threadIdx.x;
  if (idx >= rows*dcols) return;
  int c = idx % dcols, rr = idx / dcols;
  dst[idx] = (c < scols) ? (_Float16)src[(size_t)rr*sld + c] : (_Float16)0.f;
}

__global__ void addb(const float* __restrict__ a, const float* __restrict__ b,
                     float* __restrict__ o, int n)
{
  int i = blockIdx.x*256 + threadIdx.x;
  if (i < n) o[i] = a[i] + b[i];
}

__global__ void k_embed(const int* __restrict__ src, const int* __restrict__ trg,
                        const float* __restrict__ eemb, const float* __restrict__ demb,
                        _Float16* __restrict__ x_h, _Float16* __restrict__ xrev_h,
                        _Float16* __restrict__ pe_h)
{
  int idx = blockIdx.x*256 + threadIdx.x;
  const int tot1 = TSRC*NB*EMBP;
  const int tot2 = TDEC*NB*EMBP;
  if (idx < tot1) {
    int e = idx % EMBP, rb = idx / EMBP;
    int t = rb >> 6, b = rb & 63;
    float v = 0.f;
    if (e < EMBD) v = eemb[(size_t)src[rb]*EMBD + e];
    _Float16 hv = (_Float16)v;
    x_h[idx] = hv;
    xrev_h[(size_t)((TSRC-1-t)*NB + b)*EMBP + e] = hv;
  } else if (idx < tot1 + tot2) {
    int k = idx - tot1;
    int e = k % EMBP, rb = k / EMBP;
    float v = 0.f;
    if (e < EMBD) v = demb[(size_t)trg[rb]*EMBD + e];
    pe_h[k] = (_Float16)v;
  }
}

// ---------------- big tiled GEMM (throughput path), fp16 ----------------
__global__ __launch_bounds__(256) void gemm128(
    const _Float16* __restrict__ A, int lda,
    const _Float16* __restrict__ W, int ldw,
    const float* __restrict__ bias,
    float* __restrict__ out, int ldo,
    int K, int mvalid, int nvalid, int rowoff)
{
  __shared__ _Float16 As[128*64];
  __shared__ _Float16 Bs[128*64];
  const int tid = threadIdx.x;
  const int m0 = blockIdx.y*128, n0 = blockIdx.x*128;
  const int w = tid >> 6, lane = tid & 63, r = lane & 15, q = lane >> 4;
  const int mw = (w >> 1)*64, nw = (w & 1)*64;
  f32x4 acc[4][4];
#pragma unroll
  for (int mi=0; mi<4; ++mi)
#pragma unroll
    for (int ni=0; ni<4; ++ni) acc[mi][ni] = 0.f;

  for (int kt = 0; kt < K; kt += 64) {
    f16x8 ra[4], rb[4];
#pragma unroll
    for (int j = 0; j < 4; ++j) {
      int c = j*256 + tid, row = c >> 3, cc = c & 7;
      ra[j] = *(const f16x8*)(A + (size_t)(m0+row)*lda + kt + cc*8);
      rb[j] = *(const f16x8*)(W + (size_t)(n0+row)*ldw + kt + cc*8);
    }
    __syncthreads();
#pragma unroll
    for (int j = 0; j < 4; ++j) {
      int c = j*256 + tid, row = c >> 3, cc = c & 7;
      int sw = cc ^ (row & 7);
      *(f16x8*)((char*)As + row*128 + (sw<<4)) = ra[j];
      *(f16x8*)((char*)Bs + row*128 + (sw<<4)) = rb[j];
    }
    __syncthreads();
#pragma unroll
    for (int kk = 0; kk < 64; kk += 32) {
      int ch = (kk >> 3) + q;
      f16x8 av[4], bv[4];
#pragma unroll
      for (int mi=0; mi<4; ++mi) {
        int row = mw + mi*16 + r;
        av[mi] = *(const f16x8*)((char*)As + row*128 + ((ch ^ (row&7))<<4));
      }
#pragma unroll
      for (int ni=0; ni<4; ++ni) {
        int row = nw + ni*16 + r;
        bv[ni] = *(const f16x8*)((char*)Bs + row*128 + ((ch ^ (row&7))<<4));
      }
#pragma unroll
      for (int mi=0; mi<4; ++mi)
#pragma unroll
        for (int ni=0; ni<4; ++ni)
          acc[mi][ni] = __builtin_amdgcn_mfma_f32_16x16x32_f16(av[mi], bv[ni], acc[mi][ni], 0,0,0);
    }
  }
#pragma unroll
  for (int mi=0; mi<4; ++mi)
#pragma unroll
    for (int ni=0; ni<4; ++ni)
#pragma unroll
      for (int e=0; e<4; ++e) {
        int mrow = m0 + mw + mi*16 + q*4 + e;
        int col  = n0 + nw + ni*16 + r;
        if (mrow < mvalid && col < nvalid)
          out[(size_t)(mrow + rowoff)*ldo + col] = acc[mi][ni][e] + bias[col];
      }
}

// ---------------- persistent weight-stationary sequential kernel ----------------
struct SA {
  const _Float16 *whhF, *whhR;   // [2048][512]
  const _Float16 *wm1;           // [5120][1024]
  const _Float16 *wo;            // [1024][2048]
  const _Float16 *w3c;           // [4096][1024]
  const float *xpF, *xpR;        // [50*64][2048] (bias included)
  const float *pp;               // [49*64][4096] pe@dWih_pe + biases
  _Float16 *h;                   // [2 dir][2 buf][64][512]
  float *cF, *cR;                // [64][512]
  _Float16 *enc_out;             // [50][64][1024]
  _Float16 *dh;                  // [64][1024]
  float *dc;                     // [64][1024]
  float *q;                      // [64][1024]
  float *gh;                     // [64][4096]
  _Float16 *st, *ct;             // [64][1024]
  _Float16 *hdec;                // [3200][1024]
  int *flags;                    // 5 flag arrays (FE, FA, FB, FC, FD)
};

__global__ __launch_bounds__(256, 1) void seq_kernel(SA a)
{
  extern __shared__ char lds[];
  const int tid = threadIdx.x, w = tid >> 6, lane = tid & 63;
  const int wgid = blockIdx.x;
  const int r = lane & 15, q4 = lane >> 4;
  float (*sm4)[64][16] = (float(*)[64][16])(lds + LDS_SCR);
  float* qs = (float*)(lds + LDS_SCR);          // P2 only (aliases sm4)
  float* sc = (float*)(lds + LDS_SCR + 4096);

  // ---- stage this WG's weight units into LDS (once) ----
  for (int s = 0; s < 2; ++s) {
    int u = wgid + s*GRIDN;
    if (u >= NUNITS) break;
    char* dst = lds + s*65536;
    if (u < 64) {
      int dir = u >> 5, j0 = (u & 31) << 4;
      const _Float16* whh = dir ? a.whhR : a.whhF;
      for (int g = 0; g < 4; ++g)
        stageW(dst + g*16384, whh + (size_t)(g*EH + j0)*EH, EH, 16, 512, tid);
    } else if (u < 224) {
      stageW(dst, a.wm1 + (size_t)(u-64)*32*DH, DH, 32, 1024, tid);
    } else if (u < 288) {
      stageW(dst, a.wo + (size_t)(u-224)*16*2048, 2048, 16, 2048, tid);
    } else {
      // P4 fused: gate-interleaved rows {g*1024 + j0 + 0..7}, g=0..3
      int i = u - 288, j0 = i*8;
      for (int g = 0; g < 4; ++g)
        stageW(dst + g*8*2048, a.w3c + (size_t)(g*1024 + j0)*DH, DH, 8, 1024, tid);
    }
  }
  __syncthreads();

  int* FE = a.flags + 0*GRIDN*FSTRIDE;
  int* FA = a.flags + 1*GRIDN*FSTRIDE;
  int* FB = a.flags + 2*GRIDN*FSTRIDE;
  int* FC = a.flags + 3*GRIDN*FSTRIDE;
  int* FD = a.flags + 4*GRIDN*FSTRIDE;

  const bool isEnc = (wgid < 64);
  const bool isP1  = (wgid >= 64 && wgid < 224);
  const bool isP2  = (wgid < 64);
  const bool isP3  = (wgid < 40) || (wgid >= 224);
  const bool isP4  = (wgid >= 40 && wgid < 168);

  // ================= encoder: 50 steps (WGs 0-63; fwd/rev independent chains) =================
  if (isEnc) {
    const int dir = wgid >> 5, j0 = (wgid & 31) << 4;
    for (int t = 0; t < TSRC; ++t) {
      if (t) flagWaitIdx(FE, dir*32 + tid, tid < 32, t);
      const int cur = t & 1;
      const _Float16* H = a.h + (size_t)(dir*2 + cur)*NB*EH;
      f32x4 acc[4];
#pragma unroll
      for (int m=0;m<4;++m) acc[m] = 0.f;
      mm16L<EH>(acc, H, EH, lds + w*16384, 1024, 0, lane);
#pragma unroll
      for (int m=0;m<4;++m)
#pragma unroll
        for (int e=0;e<4;++e) sm4[w][m*16 + q4*4 + e][r] = acc[m][e];
      __syncthreads();
      const float* xp = (dir ? a.xpR : a.xpF) + (size_t)t*NB*2048;
      float* C = dir ? a.cR : a.cF;
      _Float16* Ho = a.h + (size_t)(dir*2 + (cur^1))*NB*EH;
      const int erow = dir ? (TSRC-1 - t) : t;
      for (int p = tid; p < 1024; p += 256) {
        int b = p >> 4, jj = p & 15, j = j0 + jj;
        float gi = sm4[0][b][jj] + xp[b*2048 + 0*EH + j];
        float gf = sm4[1][b][jj] + xp[b*2048 + 1*EH + j];
        float gg = sm4[2][b][jj] + xp[b*2048 + 2*EH + j];
        float go = sm4[3][b][jj] + xp[b*2048 + 3*EH + j];
        float co = C[b*EH + j];
        float cn = sigm(gf)*co + sigm(gi)*tanhf(gg);
        float hn = sigm(go)*tanhf(cn);
        cohS32(C + b*EH + j, cn);
        _Float16 hb = (_Float16)hn;
        cohS16(Ho + b*EH + j, hb);
        cohS16(a.enc_out + ((size_t)erow*NB + b)*DH + dir*EH + j, hb);
        if (t == TSRC-1) {
          cohS16(a.dh + b*DH + 2*j + dir, hb);
          cohS32(a.dc + b*DH + 2*j + dir, cn);
        }
      }
      flagSet(FE, wgid, t+1);
    }
  }

  // ================= decoder: 49 steps =================
  for (int t = 0; t < TDEC; ++t) {
    // ---- P1 (WGs 64-223): q|gh = dh @ [wi ; dWhh]^T ----
    if (isP1) {
      if (t == 0) flagWaitIdx(FE, tid, tid < 64, TSRC);
      else        flagWaitIdx(FD, 40 + tid, tid < 128, t);
      const int col0 = (wgid - 64)*32;
      const int cs = w >> 1, kh = w & 1;
      f32x4 acc[4];
#pragma unroll
      for (int m=0;m<4;++m) acc[m] = 0.f;
      mm16L<512>(acc, a.dh + kh*512, DH, lds + cs*16*2048, 2048, kh*1024, lane);
#pragma unroll
      for (int m=0;m<4;++m)
#pragma unroll
        for (int e=0;e<4;++e) sm4[w][m*16 + q4*4 + e][r] = acc[m][e];
      __syncthreads();
      for (int p = tid; p < 2048; p += 256) {
        int b = p >> 5, cc = p & 31;
        float v = sm4[(cc>>4)*2][b][cc&15] + sm4[(cc>>4)*2 + 1][b][cc&15];
        int C = col0 + cc;
        if (C < 1024) cohS32(a.q + b*DH + C, v);
        else          cohS32(a.gh + (size_t)b*4096 + C - 1024, v);
      }
      flagSet(FA, wgid, t+1);
    }

    // ---- P2 (WGs 0-63): attention, one batch element each ----
    if (isP2) {
      flagWaitIdx(FA, 64 + tid, tid < 160, t+1);
      const int b = wgid;
      for (int i = tid; i < 1024; i += 256) qs[i] = a.q[b*DH + i];
      __syncthreads();
      for (int tt = w; tt < TSRC; tt += 4) {
        const _Float16* er = a.enc_out + ((size_t)tt*NB + b)*DH + lane*16;
        const float* qq = qs + lane*16;
        f16x8 e0 = *(const f16x8*)(er);
        f16x8 e1 = *(const f16x8*)(er + 8);
        float s = 0.f;
#pragma unroll
        for (int ii=0; ii<8; ++ii) s += (float)e0[ii]*qq[ii];
#pragma unroll
        for (int ii=0; ii<8; ++ii) s += (float)e1[ii]*qq[8+ii];
#pragma unroll
        for (int o=32; o; o>>=1) s += __shfl_xor(s, o);
        if (lane == 0) sc[tt] = s;
      }
      __syncthreads();
      float mx = -1e30f;
      for (int tt=0; tt<TSRC; ++tt) mx = fmaxf(mx, sc[tt]);
      __syncthreads();
      if (tid < TSRC) sc[tid] = expf(sc[tid] - mx);
      __syncthreads();
      float s50 = 0.f;
      for (int tt=0; tt<TSRC; ++tt) s50 += sc[tt];
      const float inv = 1.f/s50;
      const int c0 = tid*4;
      float a0=0.f, a1=0.f, a2=0.f, a3=0.f;
      for (int tt=0; tt<TSRC; ++tt) {
        float wt = sc[tt];
        const _Float16* er = a.enc_out + ((size_t)tt*NB + b)*DH + c0;
        a0 += wt*(float)er[0]; a1 += wt*(float)er[1];
        a2 += wt*(float)er[2]; a3 += wt*(float)er[3];
      }
      cohS16(a.st + b*DH + c0 + 0, (_Float16)(a0*inv));
      cohS16(a.st + b*DH + c0 + 1, (_Float16)(a1*inv));
      cohS16(a.st + b*DH + c0 + 2, (_Float16)(a2*inv));
      cohS16(a.st + b*DH + c0 + 3, (_Float16)(a3*inv));
      flagSet(FB, wgid, t+1);
    }

    // ---- P3 (WGs 224-247 slot0 + 0-39 slot1): ct = tanh([st,dh] @ wo^T) ----
    if (isP3) {
      flagWaitIdx(FB, tid, tid < 64, t+1);
      const bool p0 = (wgid >= 224);
      const int idx  = p0 ? (wgid - 224) : (wgid + 24);
      const char* ldsB = lds + (p0 ? 0 : 65536);
      const int col0 = idx*16;
      const _Float16* A = (w < 2 ? a.st : a.dh) + (w & 1)*512;
      f32x4 acc[4];
#pragma unroll
      for (int m=0;m<4;++m) acc[m] = 0.f;
      mm16L<512>(acc, A, DH, ldsB, 4096, w*1024, lane);
#pragma unroll
      for (int m=0;m<4;++m)
#pragma unroll
        for (int e=0;e<4;++e) sm4[w][m*16 + q4*4 + e][r] = acc[m][e];
      __syncthreads();
      for (int p = tid; p < 1024; p += 256) {
        int b = p >> 4, jj = p & 15;
        float v = sm4[0][b][jj] + sm4[1][b][jj] + sm4[2][b][jj] + sm4[3][b][jj];
        cohS16(a.ct + b*DH + col0 + jj, (_Float16)tanhf(v));
      }
      flagSet(FC, wgid, t+1);
    }

    // ---- P4 (WGs 40-167): fused gates matmul + LSTM update (8 j-cols, all 4 gates) ----
    if (isP4) {
      flagWaitIdx(FC, (tid < 24) ? (224 + tid) : (tid - 24), tid < 64, t+1);
      const int j0 = (wgid - 40)*8;
      const int cs = w >> 1, kh = w & 1;
      f32x4 acc[4];
#pragma unroll
      for (int m=0;m<4;++m) acc[m] = 0.f;
      mm16L<512>(acc, a.ct + kh*512, DH, lds + 65536 + cs*16*2048, 2048, kh*1024, lane);
#pragma unroll
      for (int m=0;m<4;++m)
#pragma unroll
        for (int e=0;e<4;++e) sm4[w][m*16 + q4*4 + e][r] = acc[m][e];
      __syncthreads();
      const float* pp = a.pp + (size_t)t*NB*4096;
      for (int p = tid; p < 512; p += 256) {
        int b = p >> 3, jj = p & 7, j = j0 + jj;
        float g0 = sm4[0][b][jj]      + sm4[1][b][jj];
        float g1 = sm4[0][b][8+jj]    + sm4[1][b][8+jj];
        float g2 = sm4[2][b][jj]      + sm4[3][b][jj];
        float g3 = sm4[2][b][8+jj]    + sm4[3][b][8+jj];
        float gi = g0 + a.gh[(size_t)b*4096 + 0*DH + j] + pp[(size_t)b*4096 + 0*DH + j];
        float gf = g1 + a.gh[(size_t)b*4096 + 1*DH + j] + pp[(size_t)b*4096 + 1*DH + j];
        float gg = g2 + a.gh[(size_t)b*4096 + 2*DH + j] + pp[(size_t)b*4096 + 2*DH + j];
        float go = g3 + a.gh[(size_t)b*4096 + 3*DH + j] + pp[(size_t)b*4096 + 3*DH + j];
        float co = a.dc[b*DH + j];
        float cn = sigm(gf)*co + sigm(gi)*tanhf(gg);
        float hn = sigm(go)*tanhf(cn);
        cohS32(a.dc + b*DH + j, cn);
        _Float16 hb = (_Float16)hn;
        cohS16(a.dh + b*DH + j, hb);
        cohS16(a.hdec + ((size_t)t*NB + b)*DH + j, hb);
      }
      flagSet(FD, wgid, t+1);
    }
  }
}

// ---------------- in-place log-softmax over vocab rows ----------------
__global__ __launch_bounds__(256) void lsm(float* __restrict__ out)
{
  const int row = NB + blockIdx.x;  // rows 64..3199
  float* p = out + (size_t)row*GV;
  const int tid = threadIdx.x;
  __shared__ float red[4], red2[4];
  float mx = -1e30f;
  for (int i = tid; i < GV; i += 256) mx = fmaxf(mx, p[i]);
  for (int off=32; off; off>>=1) mx = fmaxf(mx, __shfl_down(mx, off));
  if ((tid & 63) == 0) red[tid>>6] = mx;
  __syncthreads();
  mx = fmaxf(fmaxf(red[0],red[1]), fmaxf(red[2],red[3]));
  float sm = 0.f;
  for (int i = tid; i < GV; i += 256) sm += expf(p[i] - mx);
  for (int off=32; off; off>>=1) sm += __shfl_down(sm, off);
  if ((tid & 63) == 0) red2[tid>>6] = sm;
  __syncthreads();
  sm = red2[0]+red2[1]+red2[2]+red2[3];
  float lse = mx + logf(sm);
  for (int i = tid; i < GV; i += 256) p[i] -= lse;
}

// ---------------- host ----------------
extern "C" void kernel_launch(void* const* d_in, const int* in_sizes, int n_in,
                              void* d_out, int out_size, void* d_ws, size_t ws_size,
                              hipStream_t stream)
{
  const int*   src  = (const int*)d_in[0];
  const int*   trg  = (const int*)d_in[1];
  const float* WihF = (const float*)d_in[2];
  const float* WhhF = (const float*)d_in[3];
  const float* bihF = (const float*)d_in[4];
  const float* bhhF = (const float*)d_in[5];
  const float* WihR = (const float*)d_in[6];
  const float* WhhR = (const float*)d_in[7];
  const float* bihR = (const float*)d_in[8];
  const float* bhhR = (const float*)d_in[9];
  const float* dWih = (const float*)d_in[10];
  const float* dWhh = (const float*)d_in[11];
  const float* dbih = (const float*)d_in[12];
  const float* dbhh = (const float*)d_in[13];
  const float* eemb = (const float*)d_in[14];
  const float* demb = (const float*)d_in[15];
  const float* wi   = (const float*)d_in[16];
  const float* wo   = (const float*)d_in[17];
  const float* genw = (const float*)d_in[18];
  const float* genb = (const float*)d_in[19];
  float* out = (float*)d_out;

  char* ws = (char*)d_ws;
  size_t off = 0;
  auto alloc = [&](size_t bytes)->char* {
    char* p = ws + off; off = (off + bytes + 255) & ~(size_t)255; return p;
  };
  _Float16* x_h    = (_Float16*)alloc((size_t)TSRC*NB*EMBP*2);
  _Float16* xrev_h = (_Float16*)alloc((size_t)TSRC*NB*EMBP*2);
  _Float16* pe_h   = (_Float16*)alloc((size_t)TDEC*NB*EMBP*2);
  _Float16* wihF_h = (_Float16*)alloc((size_t)2048*EMBP*2);
  _Float16* wihR_h = (_Float16*)alloc((size_t)2048*EMBP*2);
  _Float16* whhF_h = (_Float16*)alloc((size_t)2048*EH*2);
  _Float16* whhR_h = (_Float16*)alloc((size_t)2048*EH*2);
  _Float16* wm1_h  = (_Float16*)alloc((size_t)5120*DH*2);
  _Float16* wo_h   = (_Float16*)alloc((size_t)DH*2048*2);
  _Float16* w3c    = (_Float16*)alloc((size_t)4096*DH*2);
  _Float16* w3pe   = (_Float16*)alloc((size_t)4096*EMBP*2);
  _Float16* genw_h = (_Float16*)alloc((size_t)GVP*DH*2);
  float* b4f   = (float*)alloc(2048*4);
  float* b4r   = (float*)alloc(2048*4);
  float* db4   = (float*)alloc(4096*4);
  float* xp_f  = (float*)alloc((size_t)TSRC*NB*2048*4);
  float* xp_r  = (float*)alloc((size_t)TSRC*NB*2048*4);
  float* peproj = (float*)alloc((size_t)TDEC*NB*4096*4);
  _Float16* enc_out = (_Float16*)alloc((size_t)TSRC*NB*DH*2);
  _Float16* hbuf = (_Float16*)alloc((size_t)4*NB*EH*2);
  float* cf = (float*)alloc((size_t)NB*EH*4);
  float* cr = (float*)alloc((size_t)NB*EH*4);
  _Float16* dh = (_Float16*)alloc((size_t)NB*DH*2);
  float* dc = (float*)alloc((size_t)NB*DH*4);
  float* qb = (float*)alloc((size_t)NB*DH*4);
  float* gh = (float*)alloc((size_t)NB*4096*4);
  _Float16* st = (_Float16*)alloc((size_t)NB*DH*2);
  _Float16* ct = (_Float16*)alloc((size_t)NB*DH*2);
  _Float16* hdec = (_Float16*)alloc((size_t)3200*DH*2);
  int* flags = (int*)alloc(5*GRIDN*FSTRIDE*4);
  (void)in_sizes; (void)n_in; (void)out_size; (void)ws_size;

  // --- init / zero state (every call: graph replays don't re-poison) ---
  hipMemsetAsync(hbuf, 0, (size_t)4*NB*EH*2, stream);
  hipMemsetAsync(cf, 0, (size_t)NB*EH*4, stream);
  hipMemsetAsync(cr, 0, (size_t)NB*EH*4, stream);
  hipMemsetAsync(hdec + (size_t)3136*DH, 0, (size_t)64*DH*2, stream);
  hipMemsetAsync(genw_h + (size_t)GV*DH, 0, (size_t)(GVP-GV)*DH*2, stream);
  hipMemsetAsync(out, 0, (size_t)NB*GV*4, stream);   // timestep 0 = zeros
  hipMemsetAsync(flags, 0, 5*GRIDN*FSTRIDE*4, stream);

  auto cgrid = [](size_t n){ return dim3((unsigned)((n + 255)/256)); };

  // --- weight conversion (fp16) ---
  cvt16s<<<cgrid((size_t)2048*EMBP),256,0,stream>>>(WihF, wihF_h, 2048, EMBD, EMBD, EMBP);
  cvt16s<<<cgrid((size_t)2048*EMBP),256,0,stream>>>(WihR, wihR_h, 2048, EMBD, EMBD, EMBP);
  cvt16s<<<cgrid((size_t)2048*EH),256,0,stream>>>(WhhF, whhF_h, 2048, EH, EH, EH);
  cvt16s<<<cgrid((size_t)2048*EH),256,0,stream>>>(WhhR, whhR_h, 2048, EH, EH, EH);
  cvt16s<<<cgrid((size_t)1024*DH),256,0,stream>>>(wi, wm1_h, 1024, DH, DH, DH);
  cvt16s<<<cgrid((size_t)4096*DH),256,0,stream>>>(dWhh, wm1_h + (size_t)1024*DH, 4096, DH, DH, DH);
  cvt16s<<<cgrid((size_t)DH*2048),256,0,stream>>>(wo, wo_h, DH, 2048, 2048, 2048);
  cvt16s<<<cgrid((size_t)4096*DH),256,0,stream>>>(dWih, w3c, 4096, 1324, 1024, 1024);
  cvt16s<<<cgrid((size_t)4096*EMBP),256,0,stream>>>(dWih + 1024, w3pe, 4096, 1324, 300, EMBP);
  cvt16s<<<cgrid((size_t)GV*DH),256,0,stream>>>(genw, genw_h, GV, DH, DH, DH);
  addb<<<cgrid(2048),256,0,stream>>>(bihF, bhhF, b4f, 2048);
  addb<<<cgrid(2048),256,0,stream>>>(bihR, bhhR, b4r, 2048);
  addb<<<cgrid(4096),256,0,stream>>>(dbih, dbhh, db4, 4096);
  k_embed<<<cgrid((size_t)(TSRC+TDEC)*NB*EMBP),256,0,stream>>>(src, trg, eemb, demb, x_h, xrev_h, pe_h);

  // --- encoder input projections (bias folded in) + pe projection for decoder ---
  gemm128<<<dim3(16,25),256,0,stream>>>(x_h,    EMBP, wihF_h, EMBP, b4f, xp_f, 2048, EMBP, 3200, 2048, 0);
  gemm128<<<dim3(16,25),256,0,stream>>>(xrev_h, EMBP, wihR_h, EMBP, b4r, xp_r, 2048, EMBP, 3200, 2048, 0);
  gemm128<<<dim3(32,25),256,0,stream>>>(pe_h, EMBP, w3pe, EMBP, db4, peproj, 4096, EMBP, 3136, 4096, 0);

  // --- persistent weight-stationary sequential kernel ---
  SA sa;
  sa.whhF = whhF_h; sa.whhR = whhR_h;
  sa.wm1 = wm1_h;
  sa.wo = wo_h;
  sa.w3c = w3c;
  sa.xpF = xp_f; sa.xpR = xp_r;
  sa.pp = peproj;
  sa.h = hbuf;
  sa.cF = cf; sa.cR = cr;
  sa.enc_out = enc_out;
  sa.dh = dh; sa.dc = dc;
  sa.q = qb; sa.gh = gh;
  sa.st = st; sa.ct = ct;
  sa.hdec = hdec;
  sa.flags = flags;
  hipFuncSetAttribute((const void*)seq_kernel,
                      hipFuncAttributeMaxDynamicSharedMemorySize, LDS_TOT);
  seq_kernel<<<dim3(GRIDN), 256, LDS_TOT, stream>>>(sa);

  // --- generator: logits into d_out rows 64.. (t+1 shift), then log-softmax ---
  gemm128<<<dim3(GVP/128,25),256,0,stream>>>(hdec, DH, genw_h, DH, genb, out, GV, DH, 3136, GV, NB);
  lsm<<<3136,256,0,stream>>>(out);
}